// Round 1
// baseline (1309.705 us; speedup 1.0000x reference)
//
#include <hip/hip_runtime.h>
#include <cmath>
#include <cstdint>
#include <cstddef>

typedef __bf16 bf16_t;
typedef __bf16 bf16x8 __attribute__((ext_vector_type(8)));
typedef float  f32x4  __attribute__((ext_vector_type(4)));

#define B_   2
#define T_   2048
#define E_   1024
#define H_   16
#define D_   64
#define FF_  4096
#define NROW (B_ * T_)   // 4096

// ---------------------------------------------------------------- LN ----
// One block per row; 256 threads, 4 elems each. fp32 math, bf16 output.
__global__ __launch_bounds__(256) void ln_kernel(
    const float* __restrict__ x, const float* __restrict__ g,
    const float* __restrict__ bta, bf16_t* __restrict__ out)
{
    int row = blockIdx.x;
    int tid = threadIdx.x;
    const float4* xr = (const float4*)(x + (size_t)row * E_);
    float4 v = xr[tid];
    float s  = v.x + v.y + v.z + v.w;
    float ss = v.x * v.x + v.y * v.y + v.z * v.z + v.w * v.w;
#pragma unroll
    for (int off = 32; off; off >>= 1) {
        s  += __shfl_xor(s, off);
        ss += __shfl_xor(ss, off);
    }
    __shared__ float red[8];
    int wave = tid >> 6, lane = tid & 63;
    if (lane == 0) { red[wave] = s; red[4 + wave] = ss; }
    __syncthreads();
    s  = red[0] + red[1] + red[2] + red[3];
    ss = red[4] + red[5] + red[6] + red[7];
    float mu   = s * (1.0f / E_);
    float var  = ss * (1.0f / E_) - mu * mu;
    float rstd = rsqrtf(var + 1e-5f);
    float4 gv = ((const float4*)g)[tid];
    float4 bv = ((const float4*)bta)[tid];
    union { bf16_t h[4]; ushort4 u; } pk;
    pk.h[0] = (bf16_t)((v.x - mu) * rstd * gv.x + bv.x);
    pk.h[1] = (bf16_t)((v.y - mu) * rstd * gv.y + bv.y);
    pk.h[2] = (bf16_t)((v.z - mu) * rstd * gv.z + bv.z);
    pk.h[3] = (bf16_t)((v.w - mu) * rstd * gv.w + bv.w);
    ((ushort4*)(out + (size_t)row * E_))[tid] = pk.u;
}

// -------------------------------------------- weight transpose + cvt ----
// W[K][N] fp32  ->  Wt[N][K] bf16.  Block = 256 flat (32x8 logical).
__global__ __launch_bounds__(256) void transpose_cvt(
    const float* __restrict__ W, bf16_t* __restrict__ Wt, int K, int N)
{
    __shared__ float t[32][33];
    int n0 = blockIdx.x * 32, k0 = blockIdx.y * 32;
    int tx = threadIdx.x & 31, ty = threadIdx.x >> 5;
#pragma unroll
    for (int i = 0; i < 4; ++i)
        t[ty + i * 8][tx] = W[(size_t)(k0 + ty + i * 8) * N + n0 + tx];
    __syncthreads();
#pragma unroll
    for (int i = 0; i < 4; ++i)
        Wt[(size_t)(n0 + ty + i * 8) * K + k0 + tx] = (bf16_t)t[tx][ty + i * 8];
}

// ----------------------------------------------------------- GEMM ------
// C[M][N] = A[M][K] @ Bt[N][K]^T  (both bf16 row-major, K-contiguous).
// 128x128 tile, BK=32, 4 waves, each wave 4x4 mfma_16x16x32 accs (m93 shape).
#define BM 128
#define BN 128
#define BK 32
#define APAD 40   // +8 bf16 pad: spreads LDS banks, keeps 16B alignment (80B rows)

__global__ __launch_bounds__(256) void gemm_bt(
    const bf16_t* __restrict__ A, const bf16_t* __restrict__ Bt,
    const float* __restrict__ bias, const float* __restrict__ resid,
    void* __restrict__ Cout, int M, int N, int K,
    int has_bias, int do_relu, int has_resid, int out_bf16)
{
    __shared__ bf16_t As[BM * APAD];
    __shared__ bf16_t Bs[BN * APAD];
    int tid  = threadIdx.x;
    int lane = tid & 63, wave = tid >> 6;
    int m0 = blockIdx.x * BM, n0 = blockIdx.y * BN;
    int wm = (wave & 1) * 64, wn = (wave >> 1) * 64;
    f32x4 acc[4][4];
#pragma unroll
    for (int i = 0; i < 4; ++i)
#pragma unroll
        for (int j = 0; j < 4; ++j) acc[i][j] = (f32x4){0.f, 0.f, 0.f, 0.f};

    int lr = tid >> 2;          // staging row 0..63 (+64 on 2nd chunk)
    int lc = (tid & 3) * 8;     // staging col {0,8,16,24}
    const int kq = (lane >> 4) * 8;   // fragment k-offset per quad
    const int ml = lane & 15;         // fragment m/n index

    for (int k0 = 0; k0 < K; k0 += BK) {
#pragma unroll
        for (int i = 0; i < 2; ++i) {
            int r = lr + i * 64;
            *(uint4*)&As[r * APAD + lc] =
                *(const uint4*)&A[(size_t)(m0 + r) * K + k0 + lc];
            *(uint4*)&Bs[r * APAD + lc] =
                *(const uint4*)&Bt[(size_t)(n0 + r) * K + k0 + lc];
        }
        __syncthreads();
        bf16x8 af[4], bfr[4];
#pragma unroll
        for (int mi = 0; mi < 4; ++mi)
            af[mi] = *(const bf16x8*)&As[(wm + mi * 16 + ml) * APAD + kq];
#pragma unroll
        for (int ni = 0; ni < 4; ++ni)
            bfr[ni] = *(const bf16x8*)&Bs[(wn + ni * 16 + ml) * APAD + kq];
#pragma unroll
        for (int mi = 0; mi < 4; ++mi)
#pragma unroll
            for (int ni = 0; ni < 4; ++ni)
                acc[mi][ni] = __builtin_amdgcn_mfma_f32_16x16x32_bf16(
                    af[mi], bfr[ni], acc[mi][ni], 0, 0, 0);
        __syncthreads();
    }

    // epilogue: C/D layout col=lane&15, row=(lane>>4)*4+reg (verified m89/m91)
    int r4 = (lane >> 4) * 4;
#pragma unroll
    for (int mi = 0; mi < 4; ++mi) {
#pragma unroll
        for (int ni = 0; ni < 4; ++ni) {
            int col = n0 + wn + ni * 16 + ml;
            float bval = has_bias ? bias[col] : 0.0f;
#pragma unroll
            for (int r = 0; r < 4; ++r) {
                int row = m0 + wm + mi * 16 + r4 + r;
                float v = acc[mi][ni][r] + bval;
                if (do_relu)   v = fmaxf(v, 0.0f);
                if (has_resid) v += resid[(size_t)row * N + col];
                if (out_bf16)
                    ((bf16_t*)Cout)[(size_t)row * N + col] = (bf16_t)v;
                else
                    ((float*)Cout)[(size_t)row * N + col] = v;
            }
        }
    }
}

// ------------------------------------------------------- attention -----
// Flash-style online softmax, scalar VALU. One block = 16 consecutive q
// rows of one (b,h); each wave owns 4 rows; K/V staged 64 keys at a time.
__device__ inline void unpack8(uint4 u, float* f) {
    f[0] = __uint_as_float(u.x << 16);
    f[1] = __uint_as_float(u.x & 0xffff0000u);
    f[2] = __uint_as_float(u.y << 16);
    f[3] = __uint_as_float(u.y & 0xffff0000u);
    f[4] = __uint_as_float(u.z << 16);
    f[5] = __uint_as_float(u.z & 0xffff0000u);
    f[6] = __uint_as_float(u.w << 16);
    f[7] = __uint_as_float(u.w & 0xffff0000u);
}

__global__ __launch_bounds__(256) void attn_kernel(
    const bf16_t* __restrict__ Q, const bf16_t* __restrict__ Kc,
    const bf16_t* __restrict__ Vc, bf16_t* __restrict__ O)
{
    __shared__ float Ks[64][68];   // 68-stride: float4-aligned rows (272B)
    __shared__ float Vs[64][68];
    __shared__ float qs[16][64];
    __shared__ float ps[16][64];
    int tid = threadIdx.x, lane = tid & 63, wave = tid >> 6;
    const int bpb = T_ / 16;                 // 128 blocks per (b,h)
    int bh = blockIdx.x / bpb;
    int q0 = (blockIdx.x % bpb) * 16;
    int b = bh >> 4, h = bh & 15;
    size_t base = (size_t)b * T_ * E_ + h * D_;

    // stage 16 q rows (fp32)
#pragma unroll
    for (int i = 0; i < 4; ++i) {
        int v = tid + i * 256;
        int r = v >> 6, d = v & 63;
        qs[r][d] = (float)Q[base + (size_t)(q0 + r) * E_ + d];
    }
    float mrow[4], lrow[4], orow[4];
#pragma unroll
    for (int r = 0; r < 4; ++r) { mrow[r] = -INFINITY; lrow[r] = 0.f; orow[r] = 0.f; }
    int qbase = q0 + wave * 4;
    int nch = q0 / 64 + 1;                   // causal chunk count (block-uniform)

    for (int ch = 0; ch < nch; ++ch) {
        __syncthreads();                     // prev reads done before restage
#pragma unroll
        for (int i = 0; i < 2; ++i) {
            int v = tid + i * 256;
            int r = v >> 3, c8 = (v & 7) * 8;
            size_t g = base + (size_t)(ch * 64 + r) * E_ + c8;
            uint4 ku = *(const uint4*)&Kc[g];
            uint4 vu = *(const uint4*)&Vc[g];
            float tk[8], tv[8];
            unpack8(ku, tk); unpack8(vu, tv);
            *(f32x4*)&Ks[r][c8]     = *(f32x4*)&tk[0];
            *(f32x4*)&Ks[r][c8 + 4] = *(f32x4*)&tk[4];
            *(f32x4*)&Vs[r][c8]     = *(f32x4*)&tv[0];
            *(f32x4*)&Vs[r][c8 + 4] = *(f32x4*)&tv[4];
        }
        __syncthreads();

        // scores: lane j = key index within chunk
        int kidx = ch * 64 + lane;
        float sacc[4] = {0.f, 0.f, 0.f, 0.f};
        const f32x4* krow = (const f32x4*)&Ks[lane][0];
#pragma unroll
        for (int d4 = 0; d4 < 16; ++d4) {
            f32x4 kv = krow[d4];
#pragma unroll
            for (int r = 0; r < 4; ++r) {
                f32x4 qv = *(const f32x4*)&qs[wave * 4 + r][d4 * 4];
                sacc[r] += kv[0] * qv[0] + kv[1] * qv[1] + kv[2] * qv[2] + kv[3] * qv[3];
            }
        }
        float alpha[4];
#pragma unroll
        for (int r = 0; r < 4; ++r) {
            bool ok = (kidx <= qbase + r);
            float s = ok ? sacc[r] * 0.125f : -INFINITY;
            float mc = s;
#pragma unroll
            for (int off = 32; off; off >>= 1) mc = fmaxf(mc, __shfl_xor(mc, off));
            float mn = fmaxf(mrow[r], mc);
            alpha[r] = __expf(mrow[r] - mn);
            float p = ok ? __expf(s - mn) : 0.f;
            ps[wave * 4 + r][lane] = p;
            float psum = p;
#pragma unroll
            for (int off = 32; off; off >>= 1) psum += __shfl_xor(psum, off);
            lrow[r] = lrow[r] * alpha[r] + psum;
            mrow[r] = mn;
        }
        __syncthreads();                     // ps visible to all lanes

        // PV: lane = output dim d
        float oacc[4] = {0.f, 0.f, 0.f, 0.f};
#pragma unroll
        for (int j4 = 0; j4 < 16; ++j4) {
            f32x4 pv[4];
#pragma unroll
            for (int r = 0; r < 4; ++r)
                pv[r] = *(const f32x4*)&ps[wave * 4 + r][j4 * 4];
#pragma unroll
            for (int jj = 0; jj < 4; ++jj) {
                float vv = Vs[j4 * 4 + jj][lane];
#pragma unroll
                for (int r = 0; r < 4; ++r) oacc[r] += pv[r][jj] * vv;
            }
        }
#pragma unroll
        for (int r = 0; r < 4; ++r) orow[r] = orow[r] * alpha[r] + oacc[r];
    }
#pragma unroll
    for (int r = 0; r < 4; ++r)
        O[base + (size_t)(qbase + r) * E_ + lane] = (bf16_t)(orow[r] / lrow[r]);
}

// ------------------------------------------------------------ launch ---
extern "C" void kernel_launch(void* const* d_in, const int* in_sizes, int n_in,
                              void* d_out, int out_size, void* d_ws, size_t ws_size,
                              hipStream_t stream)
{
    const float* x    = (const float*)d_in[0];
    const float* ln1g = (const float*)d_in[1];
    const float* ln1b = (const float*)d_in[2];
    const float* Wq   = (const float*)d_in[3];
    const float* Wk   = (const float*)d_in[4];
    const float* Wv   = (const float*)d_in[5];
    const float* Wo   = (const float*)d_in[6];
    const float* bo   = (const float*)d_in[7];
    const float* ln2g = (const float*)d_in[8];
    const float* ln2b = (const float*)d_in[9];
    const float* W1   = (const float*)d_in[10];
    const float* b1   = (const float*)d_in[11];
    const float* W2   = (const float*)d_in[12];
    const float* b2   = (const float*)d_in[13];

    char* ws = (char*)d_ws;
    const size_t MB = 1024ull * 1024ull;
    bf16_t* wqt = (bf16_t*)(ws + 0 * MB);    // 1024x1024 bf16 (Wt[N][K])
    bf16_t* wkt = (bf16_t*)(ws + 2 * MB);
    bf16_t* wvt = (bf16_t*)(ws + 4 * MB);
    bf16_t* wot = (bf16_t*)(ws + 6 * MB);
    bf16_t* w1t = (bf16_t*)(ws + 8 * MB);    // 4096x1024 bf16
    bf16_t* w2t = (bf16_t*)(ws + 16 * MB);   // 1024x4096 bf16
    bf16_t* xn  = (bf16_t*)(ws + 24 * MB);   // 4096x1024 bf16
    bf16_t* Qb  = (bf16_t*)(ws + 32 * MB);
    bf16_t* Kb  = (bf16_t*)(ws + 40 * MB);
    bf16_t* Vb  = (bf16_t*)(ws + 48 * MB);
    bf16_t* att = (bf16_t*)(ws + 56 * MB);
    float*  x1  = (float*)(ws + 64 * MB);    // 4096x1024 fp32
    bf16_t* hb  = (bf16_t*)(ws + 80 * MB);
    bf16_t* h1  = (bf16_t*)(ws + 88 * MB);   // 4096x4096 bf16 (ends at 120 MB)

    dim3 blk(256);

    // weights -> transposed bf16
    transpose_cvt<<<dim3(E_ / 32, E_ / 32), blk, 0, stream>>>(Wq, wqt, E_, E_);
    transpose_cvt<<<dim3(E_ / 32, E_ / 32), blk, 0, stream>>>(Wk, wkt, E_, E_);
    transpose_cvt<<<dim3(E_ / 32, E_ / 32), blk, 0, stream>>>(Wv, wvt, E_, E_);
    transpose_cvt<<<dim3(E_ / 32, E_ / 32), blk, 0, stream>>>(Wo, wot, E_, E_);
    transpose_cvt<<<dim3(FF_ / 32, E_ / 32), blk, 0, stream>>>(W1, w1t, E_, FF_);
    transpose_cvt<<<dim3(E_ / 32, FF_ / 32), blk, 0, stream>>>(W2, w2t, FF_, E_);

    // LN1 -> xn (bf16)
    ln_kernel<<<dim3(NROW), blk, 0, stream>>>(x, ln1g, ln1b, xn);

    // Q/K/V projections (bf16 out)
    gemm_bt<<<dim3(NROW / BM, E_ / BN), blk, 0, stream>>>(
        xn, wqt, nullptr, nullptr, Qb, NROW, E_, E_, 0, 0, 0, 1);
    gemm_bt<<<dim3(NROW / BM, E_ / BN), blk, 0, stream>>>(
        xn, wkt, nullptr, nullptr, Kb, NROW, E_, E_, 0, 0, 0, 1);
    gemm_bt<<<dim3(NROW / BM, E_ / BN), blk, 0, stream>>>(
        xn, wvt, nullptr, nullptr, Vb, NROW, E_, E_, 0, 0, 0, 1);

    // causal attention (bf16 out)
    attn_kernel<<<dim3(B_ * H_ * (T_ / 16)), blk, 0, stream>>>(Qb, Kb, Vb, att);

    // out-proj + bias + residual(x) -> x1 (fp32)
    gemm_bt<<<dim3(NROW / BM, E_ / BN), blk, 0, stream>>>(
        att, wot, bo, x, x1, NROW, E_, E_, 1, 0, 1, 0);

    // LN2 -> hb (bf16)
    ln_kernel<<<dim3(NROW), blk, 0, stream>>>(x1, ln2g, ln2b, hb);

    // MLP up + bias + relu -> h1 (bf16)
    gemm_bt<<<dim3(NROW / BM, FF_ / BN), blk, 0, stream>>>(
        hb, w1t, b1, nullptr, h1, NROW, FF_, E_, 1, 1, 0, 1);

    // MLP down + bias + residual(x1) -> d_out (fp32)
    gemm_bt<<<dim3(NROW / BM, E_ / BN), blk, 0, stream>>>(
        h1, w2t, b2, x1, (float*)d_out, NROW, E_, FF_, 1, 0, 1, 0);
}

// Round 2
// 575.670 us; speedup vs baseline: 2.2751x; 2.2751x over previous
//
#include <hip/hip_runtime.h>
#include <cmath>
#include <cstdint>
#include <cstddef>

typedef __bf16 bf16_t;
typedef __bf16 bf16x8 __attribute__((ext_vector_type(8)));
typedef float  f32x4  __attribute__((ext_vector_type(4)));

#define B_   2
#define T_   2048
#define E_   1024
#define H_   16
#define D_   64
#define FF_  4096
#define NROW (B_ * T_)   // 4096

// ---------------------------------------------------------------- LN ----
__global__ __launch_bounds__(256) void ln_kernel(
    const float* __restrict__ x, const float* __restrict__ g,
    const float* __restrict__ bta, bf16_t* __restrict__ out)
{
    int row = blockIdx.x;
    int tid = threadIdx.x;
    const float4* xr = (const float4*)(x + (size_t)row * E_);
    float4 v = xr[tid];
    float s  = v.x + v.y + v.z + v.w;
    float ss = v.x * v.x + v.y * v.y + v.z * v.z + v.w * v.w;
#pragma unroll
    for (int off = 32; off; off >>= 1) {
        s  += __shfl_xor(s, off);
        ss += __shfl_xor(ss, off);
    }
    __shared__ float red[8];
    int wave = tid >> 6, lane = tid & 63;
    if (lane == 0) { red[wave] = s; red[4 + wave] = ss; }
    __syncthreads();
    s  = red[0] + red[1] + red[2] + red[3];
    ss = red[4] + red[5] + red[6] + red[7];
    float mu   = s * (1.0f / E_);
    float var  = ss * (1.0f / E_) - mu * mu;
    float rstd = rsqrtf(var + 1e-5f);
    float4 gv = ((const float4*)g)[tid];
    float4 bv = ((const float4*)bta)[tid];
    union { bf16_t h[4]; ushort4 u; } pk;
    pk.h[0] = (bf16_t)((v.x - mu) * rstd * gv.x + bv.x);
    pk.h[1] = (bf16_t)((v.y - mu) * rstd * gv.y + bv.y);
    pk.h[2] = (bf16_t)((v.z - mu) * rstd * gv.z + bv.z);
    pk.h[3] = (bf16_t)((v.w - mu) * rstd * gv.w + bv.w);
    ((ushort4*)(out + (size_t)row * E_))[tid] = pk.u;
}

// -------------------------------------------- weight transpose + cvt ----
__global__ __launch_bounds__(256) void transpose_cvt(
    const float* __restrict__ W, bf16_t* __restrict__ Wt, int K, int N)
{
    __shared__ float t[32][33];
    int n0 = blockIdx.x * 32, k0 = blockIdx.y * 32;
    int tx = threadIdx.x & 31, ty = threadIdx.x >> 5;
#pragma unroll
    for (int i = 0; i < 4; ++i)
        t[ty + i * 8][tx] = W[(size_t)(k0 + ty + i * 8) * N + n0 + tx];
    __syncthreads();
#pragma unroll
    for (int i = 0; i < 4; ++i)
        Wt[(size_t)(n0 + ty + i * 8) * K + k0 + tx] = (bf16_t)t[tx][ty + i * 8];
}

// --------------------------------------------- V transpose (per head) ---
// Vb[b][t][h*64+d] (bf16) -> Vt[bh][d][t] (bf16). Coalesced reads (128B per
// wave-instr), 16B-granular scattered stores (8 MB total, L2-merged).
__global__ __launch_bounds__(256) void vt_kernel(
    const bf16_t* __restrict__ V, bf16_t* __restrict__ Vt)
{
    int wave = threadIdx.x >> 6, lane = threadIdx.x & 63;
    int bh = blockIdx.y, b = bh >> 4, h = bh & 15;
    int t0 = blockIdx.x * 32 + wave * 8;
    const unsigned short* src =
        (const unsigned short*)V + (size_t)(b * T_ + t0) * E_ + h * D_ + lane;
    unsigned short vals[8];
#pragma unroll
    for (int j = 0; j < 8; ++j) vals[j] = src[(size_t)j * E_];
    unsigned short* dst =
        (unsigned short*)Vt + ((size_t)bh * D_ + lane) * T_ + t0;
    *(uint4*)dst = *(uint4*)vals;
}

// ----------------------------------------------------------- GEMM ------
#define BM 128
#define BN 128
#define BK 32
#define APAD 40

__global__ __launch_bounds__(256) void gemm_bt(
    const bf16_t* __restrict__ A, const bf16_t* __restrict__ Bt,
    const float* __restrict__ bias, const float* __restrict__ resid,
    void* __restrict__ Cout, int M, int N, int K,
    int has_bias, int do_relu, int has_resid, int out_bf16)
{
    __shared__ bf16_t As[BM * APAD];
    __shared__ bf16_t Bs[BN * APAD];
    int tid  = threadIdx.x;
    int lane = tid & 63, wave = tid >> 6;
    int m0 = blockIdx.x * BM, n0 = blockIdx.y * BN;
    int wm = (wave & 1) * 64, wn = (wave >> 1) * 64;
    f32x4 acc[4][4];
#pragma unroll
    for (int i = 0; i < 4; ++i)
#pragma unroll
        for (int j = 0; j < 4; ++j) acc[i][j] = (f32x4){0.f, 0.f, 0.f, 0.f};

    int lr = tid >> 2;
    int lc = (tid & 3) * 8;
    const int kq = (lane >> 4) * 8;
    const int ml = lane & 15;

    for (int k0 = 0; k0 < K; k0 += BK) {
#pragma unroll
        for (int i = 0; i < 2; ++i) {
            int r = lr + i * 64;
            *(uint4*)&As[r * APAD + lc] =
                *(const uint4*)&A[(size_t)(m0 + r) * K + k0 + lc];
            *(uint4*)&Bs[r * APAD + lc] =
                *(const uint4*)&Bt[(size_t)(n0 + r) * K + k0 + lc];
        }
        __syncthreads();
        bf16x8 af[4], bfr[4];
#pragma unroll
        for (int mi = 0; mi < 4; ++mi)
            af[mi] = *(const bf16x8*)&As[(wm + mi * 16 + ml) * APAD + kq];
#pragma unroll
        for (int ni = 0; ni < 4; ++ni)
            bfr[ni] = *(const bf16x8*)&Bs[(wn + ni * 16 + ml) * APAD + kq];
#pragma unroll
        for (int mi = 0; mi < 4; ++mi)
#pragma unroll
            for (int ni = 0; ni < 4; ++ni)
                acc[mi][ni] = __builtin_amdgcn_mfma_f32_16x16x32_bf16(
                    af[mi], bfr[ni], acc[mi][ni], 0, 0, 0);
        __syncthreads();
    }

    int r4 = (lane >> 4) * 4;
#pragma unroll
    for (int mi = 0; mi < 4; ++mi) {
#pragma unroll
        for (int ni = 0; ni < 4; ++ni) {
            int col = n0 + wn + ni * 16 + ml;
            float bval = has_bias ? bias[col] : 0.0f;
#pragma unroll
            for (int r = 0; r < 4; ++r) {
                int row = m0 + wm + mi * 16 + r4 + r;
                float v = acc[mi][ni][r] + bval;
                if (do_relu)   v = fmaxf(v, 0.0f);
                if (has_resid) v += resid[(size_t)row * N + col];
                if (out_bf16)
                    ((bf16_t*)Cout)[(size_t)row * N + col] = (bf16_t)v;
                else
                    ((float*)Cout)[(size_t)row * N + col] = v;
            }
        }
    }
}

// ------------------------------------------------- MFMA flash attention -
// Block = 64 q rows of one (b,h); 4 waves x 16 q rows. K/V chunks of 64
// keys in LDS. QK^T and PV via mfma_16x16x32_bf16; P round-trips LDS
// (C-layout -> A-layout, m120 pattern). Stride 72 bf16 = 144 B rows:
// b128 frag reads are 2-way bank-aliased = free (m136).
#define PSTR 72

__global__ __launch_bounds__(256) void attn_mfma(
    const bf16_t* __restrict__ Q, const bf16_t* __restrict__ Kc,
    const bf16_t* __restrict__ Vt, bf16_t* __restrict__ O)
{
    __shared__ bf16_t Ks[64 * PSTR];       // [key][d]
    __shared__ bf16_t Vts[64 * PSTR];      // [d][key]
    __shared__ bf16_t Ps[4][16 * PSTR];    // per-wave P / O staging

    int tid = threadIdx.x, lane = tid & 63, wave = tid >> 6;
    int ml  = lane & 15;
    int kq8 = (lane >> 4) * 8;
    int r4  = (lane >> 4) * 4;
    int bh = blockIdx.y, b = bh >> 4, h = bh & 15;
    int q0 = blockIdx.x * 64;
    int qw = q0 + wave * 16;
    size_t qk_base = (size_t)b * T_ * E_ + h * D_;
    size_t vt_base = (size_t)bh * D_ * T_;

    // Q fragments (A layout: m=lane&15, k=quad*8+j), direct from global
    bf16x8 aq[2];
#pragma unroll
    for (int ks = 0; ks < 2; ++ks)
        aq[ks] = *(const bf16x8*)&Q[qk_base + (size_t)(qw + ml) * E_ + ks * 32 + kq8];

    f32x4 acc[4];
#pragma unroll
    for (int dt = 0; dt < 4; ++dt) acc[dt] = (f32x4){0.f, 0.f, 0.f, 0.f};
    float m4[4] = {-INFINITY, -INFINITY, -INFINITY, -INFINITY};
    float l4[4] = {0.f, 0.f, 0.f, 0.f};

    int nch = q0 / 64 + 1;
    for (int ch = 0; ch < nch; ++ch) {
        __syncthreads();   // protect Ks/Vts WAR from previous chunk
#pragma unroll
        for (int i = 0; i < 2; ++i) {
            int v = tid + i * 256;
            int r = v >> 3, c = (v & 7) * 8;
            *(uint4*)&Ks[r * PSTR + c] =
                *(const uint4*)&Kc[qk_base + (size_t)(ch * 64 + r) * E_ + c];
            *(uint4*)&Vts[r * PSTR + c] =
                *(const uint4*)&Vt[vt_base + (size_t)r * T_ + ch * 64 + c];
        }
        __syncthreads();

        // S = Q K^T : 4 key-tiles x 2 k-steps
        f32x4 s[4];
#pragma unroll
        for (int nt = 0; nt < 4; ++nt) {
            s[nt] = (f32x4){0.f, 0.f, 0.f, 0.f};
#pragma unroll
            for (int ks = 0; ks < 2; ++ks) {
                bf16x8 bk = *(const bf16x8*)&Ks[(nt * 16 + ml) * PSTR + ks * 32 + kq8];
                s[nt] = __builtin_amdgcn_mfma_f32_16x16x32_bf16(aq[ks], bk, s[nt], 0, 0, 0);
            }
        }

        // scale + causal mask (diagonal chunk only; wave-uniform branch)
        bool last = (ch == nch - 1);
#pragma unroll
        for (int nt = 0; nt < 4; ++nt)
#pragma unroll
            for (int r = 0; r < 4; ++r) {
                float v = s[nt][r] * 0.125f;
                if (last) {
                    int key  = ch * 64 + nt * 16 + ml;
                    int qrow = qw + r4 + r;
                    if (key > qrow) v = -INFINITY;
                }
                s[nt][r] = v;
            }

        // online softmax: rows live in 16-lane groups -> shfl over 8/4/2/1
        float al[4];
#pragma unroll
        for (int r = 0; r < 4; ++r) {
            float mx = fmaxf(fmaxf(s[0][r], s[1][r]), fmaxf(s[2][r], s[3][r]));
#pragma unroll
            for (int off = 8; off; off >>= 1) mx = fmaxf(mx, __shfl_xor(mx, off));
            float mn = fmaxf(m4[r], mx);
            al[r] = __expf(m4[r] - mn);
            m4[r] = mn;
            float sum = 0.f;
#pragma unroll
            for (int nt = 0; nt < 4; ++nt) {
                float p = __expf(s[nt][r] - mn);
                s[nt][r] = p;
                sum += p;
            }
#pragma unroll
            for (int off = 8; off; off >>= 1) sum += __shfl_xor(sum, off);
            l4[r] = l4[r] * al[r] + sum;
        }

        // rescale O accumulator
#pragma unroll
        for (int dt = 0; dt < 4; ++dt)
#pragma unroll
            for (int r = 0; r < 4; ++r) acc[dt][r] *= al[r];

        // P: C-layout regs -> LDS [q][key] (bf16)
#pragma unroll
        for (int nt = 0; nt < 4; ++nt)
#pragma unroll
            for (int r = 0; r < 4; ++r)
                Ps[wave][(r4 + r) * PSTR + nt * 16 + ml] = (bf16_t)s[nt][r];
        __syncthreads();   // cross-lane P visibility (uniform count)

        // O += P V : A = P (LDS, A-layout), B = V^T (LDS)
#pragma unroll
        for (int ks = 0; ks < 2; ++ks) {
            bf16x8 ap = *(const bf16x8*)&Ps[wave][ml * PSTR + ks * 32 + kq8];
#pragma unroll
            for (int dt = 0; dt < 4; ++dt) {
                bf16x8 bv = *(const bf16x8*)&Vts[(dt * 16 + ml) * PSTR + ks * 32 + kq8];
                acc[dt] = __builtin_amdgcn_mfma_f32_16x16x32_bf16(ap, bv, acc[dt], 0, 0, 0);
            }
        }
    }

    // epilogue: normalize, stage to LDS, vectorized global store
    __syncthreads();
#pragma unroll
    for (int dt = 0; dt < 4; ++dt)
#pragma unroll
        for (int r = 0; r < 4; ++r)
            Ps[wave][(r4 + r) * PSTR + dt * 16 + ml] = (bf16_t)(acc[dt][r] / l4[r]);
    __syncthreads();
    {
        int row = lane >> 2, seg = (lane & 3) * 16;
        bf16x8 o0 = *(const bf16x8*)&Ps[wave][row * PSTR + seg];
        bf16x8 o1 = *(const bf16x8*)&Ps[wave][row * PSTR + seg + 8];
        size_t g = qk_base + (size_t)(qw + row) * E_ + seg;
        *(bf16x8*)&O[g]     = o0;
        *(bf16x8*)&O[g + 8] = o1;
    }
}

// ------------------------------------------------------------ launch ---
extern "C" void kernel_launch(void* const* d_in, const int* in_sizes, int n_in,
                              void* d_out, int out_size, void* d_ws, size_t ws_size,
                              hipStream_t stream)
{
    const float* x    = (const float*)d_in[0];
    const float* ln1g = (const float*)d_in[1];
    const float* ln1b = (const float*)d_in[2];
    const float* Wq   = (const float*)d_in[3];
    const float* Wk   = (const float*)d_in[4];
    const float* Wv   = (const float*)d_in[5];
    const float* Wo   = (const float*)d_in[6];
    const float* bo   = (const float*)d_in[7];
    const float* ln2g = (const float*)d_in[8];
    const float* ln2b = (const float*)d_in[9];
    const float* W1   = (const float*)d_in[10];
    const float* b1   = (const float*)d_in[11];
    const float* W2   = (const float*)d_in[12];
    const float* b2   = (const float*)d_in[13];

    char* ws = (char*)d_ws;
    const size_t MB = 1024ull * 1024ull;
    bf16_t* wqt = (bf16_t*)(ws + 0 * MB);
    bf16_t* wkt = (bf16_t*)(ws + 2 * MB);
    bf16_t* wvt = (bf16_t*)(ws + 4 * MB);
    bf16_t* wot = (bf16_t*)(ws + 6 * MB);
    bf16_t* w1t = (bf16_t*)(ws + 8 * MB);
    bf16_t* w2t = (bf16_t*)(ws + 16 * MB);
    bf16_t* xn  = (bf16_t*)(ws + 24 * MB);
    bf16_t* Qb  = (bf16_t*)(ws + 32 * MB);
    bf16_t* Kb  = (bf16_t*)(ws + 40 * MB);
    bf16_t* Vb  = (bf16_t*)(ws + 48 * MB);
    bf16_t* att = (bf16_t*)(ws + 56 * MB);
    float*  x1  = (float*)(ws + 64 * MB);
    bf16_t* hb  = (bf16_t*)(ws + 80 * MB);
    bf16_t* h1  = (bf16_t*)(ws + 88 * MB);   // 32 MB; also hosts Vt early
    bf16_t* Vtb = (bf16_t*)(ws + 88 * MB);   // 8 MB, dead before h1 is written

    dim3 blk(256);

    transpose_cvt<<<dim3(E_ / 32, E_ / 32), blk, 0, stream>>>(Wq, wqt, E_, E_);
    transpose_cvt<<<dim3(E_ / 32, E_ / 32), blk, 0, stream>>>(Wk, wkt, E_, E_);
    transpose_cvt<<<dim3(E_ / 32, E_ / 32), blk, 0, stream>>>(Wv, wvt, E_, E_);
    transpose_cvt<<<dim3(E_ / 32, E_ / 32), blk, 0, stream>>>(Wo, wot, E_, E_);
    transpose_cvt<<<dim3(FF_ / 32, E_ / 32), blk, 0, stream>>>(W1, w1t, E_, FF_);
    transpose_cvt<<<dim3(E_ / 32, FF_ / 32), blk, 0, stream>>>(W2, w2t, FF_, E_);

    ln_kernel<<<dim3(NROW), blk, 0, stream>>>(x, ln1g, ln1b, xn);

    gemm_bt<<<dim3(NROW / BM, E_ / BN), blk, 0, stream>>>(
        xn, wqt, nullptr, nullptr, Qb, NROW, E_, E_, 0, 0, 0, 1);
    gemm_bt<<<dim3(NROW / BM, E_ / BN), blk, 0, stream>>>(
        xn, wkt, nullptr, nullptr, Kb, NROW, E_, E_, 0, 0, 0, 1);
    gemm_bt<<<dim3(NROW / BM, E_ / BN), blk, 0, stream>>>(
        xn, wvt, nullptr, nullptr, Vb, NROW, E_, E_, 0, 0, 0, 1);

    // V -> per-head transposed layout for PV B-operand
    vt_kernel<<<dim3(T_ / 32, B_ * H_), blk, 0, stream>>>(Vb, Vtb);

    // MFMA flash attention
    attn_mfma<<<dim3(T_ / 64, B_ * H_), blk, 0, stream>>>(Qb, Kb, Vtb, att);

    gemm_bt<<<dim3(NROW / BM, E_ / BN), blk, 0, stream>>>(
        att, wot, bo, x, x1, NROW, E_, E_, 1, 0, 1, 0);

    ln_kernel<<<dim3(NROW), blk, 0, stream>>>(x1, ln2g, ln2b, hb);

    gemm_bt<<<dim3(NROW / BM, FF_ / BN), blk, 0, stream>>>(
        hb, w1t, b1, nullptr, h1, NROW, FF_, E_, 1, 1, 0, 1);

    gemm_bt<<<dim3(NROW / BM, E_ / BN), blk, 0, stream>>>(
        h1, w2t, b2, x1, (float*)d_out, NROW, E_, FF_, 1, 0, 1, 0);
}

// Round 3
// 471.268 us; speedup vs baseline: 2.7791x; 1.2215x over previous
//
#include <hip/hip_runtime.h>
#include <cmath>
#include <cstdint>
#include <cstddef>

typedef __bf16 bf16_t;
typedef __bf16 bf16x8 __attribute__((ext_vector_type(8)));
typedef float  f32x4  __attribute__((ext_vector_type(4)));

#define B_   2
#define T_   2048
#define E_   1024
#define H_   16
#define D_   64
#define FF_  4096
#define NROW (B_ * T_)   // 4096
#define QS_  (3 * E_)    // packed QKV row stride

// async global->LDS, 16B per lane (m97 pattern)
__device__ __forceinline__ void gll16(const bf16_t* g, bf16_t* l) {
    __builtin_amdgcn_global_load_lds(
        (const __attribute__((address_space(1))) unsigned int*)g,
        (__attribute__((address_space(3))) unsigned int*)l, 16, 0, 0);
}

// ---------------------------------------------------------------- LN ----
__global__ __launch_bounds__(256) void ln_kernel(
    const float* __restrict__ x, const float* __restrict__ g,
    const float* __restrict__ bta, bf16_t* __restrict__ out)
{
    int row = blockIdx.x;
    int tid = threadIdx.x;
    const float4* xr = (const float4*)(x + (size_t)row * E_);
    float4 v = xr[tid];
    float s  = v.x + v.y + v.z + v.w;
    float ss = v.x * v.x + v.y * v.y + v.z * v.z + v.w * v.w;
#pragma unroll
    for (int off = 32; off; off >>= 1) {
        s  += __shfl_xor(s, off);
        ss += __shfl_xor(ss, off);
    }
    __shared__ float red[8];
    int wave = tid >> 6, lane = tid & 63;
    if (lane == 0) { red[wave] = s; red[4 + wave] = ss; }
    __syncthreads();
    s  = red[0] + red[1] + red[2] + red[3];
    ss = red[4] + red[5] + red[6] + red[7];
    float mu   = s * (1.0f / E_);
    float var  = ss * (1.0f / E_) - mu * mu;
    float rstd = rsqrtf(var + 1e-5f);
    float4 gv = ((const float4*)g)[tid];
    float4 bv = ((const float4*)bta)[tid];
    union { bf16_t h[4]; ushort4 u; } pk;
    pk.h[0] = (bf16_t)((v.x - mu) * rstd * gv.x + bv.x);
    pk.h[1] = (bf16_t)((v.y - mu) * rstd * gv.y + bv.y);
    pk.h[2] = (bf16_t)((v.z - mu) * rstd * gv.z + bv.z);
    pk.h[3] = (bf16_t)((v.w - mu) * rstd * gv.w + bv.w);
    ((ushort4*)(out + (size_t)row * E_))[tid] = pk.u;
}

// -------------------------------------------- weight transpose + cvt ----
__global__ __launch_bounds__(256) void transpose_cvt(
    const float* __restrict__ W, bf16_t* __restrict__ Wt, int K, int N)
{
    __shared__ float t[32][33];
    int n0 = blockIdx.x * 32, k0 = blockIdx.y * 32;
    int tx = threadIdx.x & 31, ty = threadIdx.x >> 5;
#pragma unroll
    for (int i = 0; i < 4; ++i)
        t[ty + i * 8][tx] = W[(size_t)(k0 + ty + i * 8) * N + n0 + tx];
    __syncthreads();
#pragma unroll
    for (int i = 0; i < 4; ++i)
        Wt[(size_t)(n0 + ty + i * 8) * K + k0 + tx] = (bf16_t)t[tx][ty + i * 8];
}

// --------------------------------------------- V transpose (per head) ---
// V inside packed QKV (row stride QS_) -> Vt[bh][d][t].
__global__ __launch_bounds__(256) void vt_kernel(
    const bf16_t* __restrict__ V, bf16_t* __restrict__ Vt)
{
    int wave = threadIdx.x >> 6, lane = threadIdx.x & 63;
    int bh = blockIdx.y, b = bh >> 4, h = bh & 15;
    int t0 = blockIdx.x * 32 + wave * 8;
    const unsigned short* src =
        (const unsigned short*)V + (size_t)(b * T_ + t0) * QS_ + h * D_ + lane;
    unsigned short vals[8];
#pragma unroll
    for (int j = 0; j < 8; ++j) vals[j] = src[(size_t)j * QS_];
    unsigned short* dst =
        (unsigned short*)Vt + ((size_t)bh * D_ + lane) * T_ + t0;
    *(uint4*)dst = *(uint4*)vals;
}

// ----------------------------------------------------------- GEMM ------
// m97 structure: unpadded [128][32] LDS tiles, global_load_lds width=16.
#define BM 128
#define BN 128
#define BK 32

__global__ __launch_bounds__(256) void gemm_bt(
    const bf16_t* __restrict__ A, const bf16_t* __restrict__ Bt,
    const float* __restrict__ bias, const float* __restrict__ resid,
    void* __restrict__ Cout, int M, int N, int K,
    int has_bias, int do_relu, int has_resid, int out_bf16)
{
    __shared__ __attribute__((aligned(16))) bf16_t As[BM * BK];
    __shared__ __attribute__((aligned(16))) bf16_t Bs[BN * BK];
    int tid  = threadIdx.x;
    int lane = tid & 63, wave = tid >> 6;
    int m0 = blockIdx.x * BM, n0 = blockIdx.y * BN;
    int wm = (wave & 1) * 64, wn = (wave >> 1) * 64;
    f32x4 acc[4][4];
#pragma unroll
    for (int i = 0; i < 4; ++i)
#pragma unroll
        for (int j = 0; j < 4; ++j) acc[i][j] = (f32x4){0.f, 0.f, 0.f, 0.f};

    int sr = tid >> 2;            // 0..63
    int sc = (tid & 3) * 8;       // 0,8,16,24
    const int kq = (lane >> 4) * 8;
    const int ml = lane & 15;
    const bf16_t* Ag = A  + (size_t)(m0 + sr) * K + sc;
    const bf16_t* Bg = Bt + (size_t)(n0 + sr) * K + sc;
    bf16_t* Al = &As[sr * BK + sc];
    bf16_t* Bl = &Bs[sr * BK + sc];

    for (int k0 = 0; k0 < K; k0 += BK) {
        gll16(Ag + k0, Al);
        gll16(Ag + k0 + (size_t)64 * K, Al + 64 * BK);
        gll16(Bg + k0, Bl);
        gll16(Bg + k0 + (size_t)64 * K, Bl + 64 * BK);
        __syncthreads();   // drains vmcnt (data ready)
        bf16x8 af[4], bfr[4];
#pragma unroll
        for (int mi = 0; mi < 4; ++mi)
            af[mi] = *(const bf16x8*)&As[(wm + mi * 16 + ml) * BK + kq];
#pragma unroll
        for (int ni = 0; ni < 4; ++ni)
            bfr[ni] = *(const bf16x8*)&Bs[(wn + ni * 16 + ml) * BK + kq];
#pragma unroll
        for (int mi = 0; mi < 4; ++mi)
#pragma unroll
            for (int ni = 0; ni < 4; ++ni)
                acc[mi][ni] = __builtin_amdgcn_mfma_f32_16x16x32_bf16(
                    af[mi], bfr[ni], acc[mi][ni], 0, 0, 0);
        __syncthreads();   // WAR before next stage
    }

    int r4 = (lane >> 4) * 4;
#pragma unroll
    for (int mi = 0; mi < 4; ++mi) {
#pragma unroll
        for (int ni = 0; ni < 4; ++ni) {
            int col = n0 + wn + ni * 16 + ml;
            float bval = has_bias ? bias[col] : 0.0f;
#pragma unroll
            for (int r = 0; r < 4; ++r) {
                int row = m0 + wm + mi * 16 + r4 + r;
                float v = acc[mi][ni][r] + bval;
                if (do_relu)   v = fmaxf(v, 0.0f);
                if (has_resid) v += resid[(size_t)row * N + col];
                if (out_bf16)
                    ((bf16_t*)Cout)[(size_t)row * N + col] = (bf16_t)v;
                else
                    ((float*)Cout)[(size_t)row * N + col] = v;
            }
        }
    }
}

// ------------------------------------------------- MFMA flash attention -
// Transposed orientation: S^T = K Q^T, O^T = V^T P^T. All softmax state is
// per-lane scalar (q = lane&15). Paired q-tiles (i, NT-1-i) -> uniform 33
// chunks per block. Ps per-wave: write->read within wave needs no barrier.
#define PSTR 72

__global__ __launch_bounds__(256) void attn_mfma(
    const bf16_t* __restrict__ Qp, const bf16_t* __restrict__ Kp,
    const bf16_t* __restrict__ Vt, bf16_t* __restrict__ O)
{
    __shared__ __attribute__((aligned(16))) bf16_t Ks[64 * PSTR];   // [key][d]
    __shared__ __attribute__((aligned(16))) bf16_t Vts[64 * PSTR];  // [d][key]
    __shared__ __attribute__((aligned(16))) bf16_t Ps[4][16 * PSTR];

    int tid = threadIdx.x, lane = tid & 63, wave = tid >> 6;
    int ml  = lane & 15;
    int kq8 = (lane >> 4) * 8;
    int r4  = (lane >> 4) * 4;
    int bh = blockIdx.y, b = bh >> 4, h = bh & 15;
    size_t qk_base = (size_t)b * T_ * QS_ + h * D_;
    size_t vt_base = (size_t)bh * D_ * T_;
    size_t o_base  = (size_t)b * T_ * E_ + h * D_;
    const int NT = T_ / 64;

    for (int rep = 0; rep < 2; ++rep) {
        int tile = rep ? (NT - 1 - blockIdx.x) : blockIdx.x;
        int q0 = tile * 64;
        int qw = q0 + wave * 16;

        // Q fragments (B-operand: n=q, k=d), pre-scaled by 1/8 (exact in bf16)
        bf16x8 qf[2];
#pragma unroll
        for (int ks = 0; ks < 2; ++ks) {
            bf16x8 raw = *(const bf16x8*)&Qp[qk_base + (size_t)(qw + ml) * QS_ + ks * 32 + kq8];
#pragma unroll
            for (int j = 0; j < 8; ++j) raw[j] = (bf16_t)((float)raw[j] * 0.125f);
            qf[ks] = raw;
        }

        f32x4 acc[4];
#pragma unroll
        for (int dt = 0; dt < 4; ++dt) acc[dt] = (f32x4){0.f, 0.f, 0.f, 0.f};
        float m1 = -INFINITY, l1 = 0.f;

        int nch = q0 / 64 + 1;
        for (int ch = 0; ch < nch; ++ch) {
            __syncthreads();   // WAR on Ks/Vts
#pragma unroll
            for (int i = 0; i < 2; ++i) {
                int v = tid + i * 256;
                int r = v >> 3, c = (v & 7) * 8;
                *(uint4*)&Ks[r * PSTR + c] =
                    *(const uint4*)&Kp[qk_base + (size_t)(ch * 64 + r) * QS_ + c];
                *(uint4*)&Vts[r * PSTR + c] =
                    *(const uint4*)&Vt[vt_base + (size_t)r * T_ + ch * 64 + c];
            }
            __syncthreads();

            // S^T = K Q^T : A=K (m=key), B=Q (n=q)
            f32x4 s[4];
#pragma unroll
            for (int nt = 0; nt < 4; ++nt) {
                s[nt] = (f32x4){0.f, 0.f, 0.f, 0.f};
#pragma unroll
                for (int ks = 0; ks < 2; ++ks) {
                    bf16x8 kf = *(const bf16x8*)&Ks[(nt * 16 + ml) * PSTR + ks * 32 + kq8];
                    s[nt] = __builtin_amdgcn_mfma_f32_16x16x32_bf16(kf, qf[ks], s[nt], 0, 0, 0);
                }
            }

            // causal mask on diagonal chunk only (q = qw+ml, key = rows)
            if (ch == nch - 1) {
                int q = qw + ml;
#pragma unroll
                for (int nt = 0; nt < 4; ++nt)
#pragma unroll
                    for (int r = 0; r < 4; ++r)
                        if (ch * 64 + nt * 16 + r4 + r > q) s[nt][r] = -INFINITY;
            }

            // online softmax: per-lane scalar state (all 16 vals share q=ml)
            float mx = -INFINITY;
#pragma unroll
            for (int nt = 0; nt < 4; ++nt)
#pragma unroll
                for (int r = 0; r < 4; ++r) mx = fmaxf(mx, s[nt][r]);
            mx = fmaxf(mx, __shfl_xor(mx, 16));
            mx = fmaxf(mx, __shfl_xor(mx, 32));
            float mn = fmaxf(m1, mx);
            float al = __expf(m1 - mn);
            m1 = mn;
            float sum = 0.f;
#pragma unroll
            for (int nt = 0; nt < 4; ++nt)
#pragma unroll
                for (int r = 0; r < 4; ++r) {
                    float p = __expf(s[nt][r] - mn);
                    s[nt][r] = p;
                    sum += p;
                }
            sum += __shfl_xor(sum, 16);
            sum += __shfl_xor(sum, 32);
            l1 = l1 * al + sum;
#pragma unroll
            for (int dt = 0; dt < 4; ++dt)
#pragma unroll
                for (int r = 0; r < 4; ++r) acc[dt][r] *= al;

            // P^T regs -> Ps[q][key] (4x ds_write_b64; keys r4..r4+3 contiguous)
#pragma unroll
            for (int nt = 0; nt < 4; ++nt) {
                union { bf16_t h[4]; uint2 u; } pk;
#pragma unroll
                for (int r = 0; r < 4; ++r) pk.h[r] = (bf16_t)s[nt][r];
                *(uint2*)&Ps[wave][ml * PSTR + nt * 16 + r4] = pk.u;
            }
            // wave-local write->read: no barrier needed

            // O^T += V^T P^T : A=Vt (m=d), B=P (n=q)
#pragma unroll
            for (int ks = 0; ks < 2; ++ks) {
                bf16x8 pf = *(const bf16x8*)&Ps[wave][ml * PSTR + ks * 32 + kq8];
#pragma unroll
                for (int dt = 0; dt < 4; ++dt) {
                    bf16x8 vf = *(const bf16x8*)&Vts[(dt * 16 + ml) * PSTR + ks * 32 + kq8];
                    acc[dt] = __builtin_amdgcn_mfma_f32_16x16x32_bf16(vf, pf, acc[dt], 0, 0, 0);
                }
            }
        }

        // epilogue: normalize (per-lane 1/l), stage [q][d], vector store
        float inv = 1.0f / l1;
#pragma unroll
        for (int dt = 0; dt < 4; ++dt) {
            union { bf16_t h[4]; uint2 u; } pk;
#pragma unroll
            for (int r = 0; r < 4; ++r) pk.h[r] = (bf16_t)(acc[dt][r] * inv);
            *(uint2*)&Ps[wave][ml * PSTR + dt * 16 + r4] = pk.u;
        }
        {
            int row = lane >> 2, seg = (lane & 3) * 16;
            bf16x8 o0 = *(const bf16x8*)&Ps[wave][row * PSTR + seg];
            bf16x8 o1 = *(const bf16x8*)&Ps[wave][row * PSTR + seg + 8];
            size_t g = o_base + (size_t)(qw + row) * E_ + seg;
            *(bf16x8*)&O[g]     = o0;
            *(bf16x8*)&O[g + 8] = o1;
        }
    }
}

// ------------------------------------------------------------ launch ---
extern "C" void kernel_launch(void* const* d_in, const int* in_sizes, int n_in,
                              void* d_out, int out_size, void* d_ws, size_t ws_size,
                              hipStream_t stream)
{
    const float* x    = (const float*)d_in[0];
    const float* ln1g = (const float*)d_in[1];
    const float* ln1b = (const float*)d_in[2];
    const float* Wq   = (const float*)d_in[3];
    const float* Wk   = (const float*)d_in[4];
    const float* Wv   = (const float*)d_in[5];
    const float* Wo   = (const float*)d_in[6];
    const float* bo   = (const float*)d_in[7];
    const float* ln2g = (const float*)d_in[8];
    const float* ln2b = (const float*)d_in[9];
    const float* W1   = (const float*)d_in[10];
    const float* b1   = (const float*)d_in[11];
    const float* W2   = (const float*)d_in[12];
    const float* b2   = (const float*)d_in[13];

    char* ws = (char*)d_ws;
    const size_t MB = 1024ull * 1024ull;
    bf16_t* wqkv = (bf16_t*)(ws + 0 * MB);    // 3072x1024 bf16 (6 MB)
    bf16_t* wot  = (bf16_t*)(ws + 6 * MB);    // 1024x1024 bf16
    bf16_t* w1t  = (bf16_t*)(ws + 8 * MB);    // 4096x1024 bf16
    bf16_t* w2t  = (bf16_t*)(ws + 16 * MB);   // 1024x4096 bf16
    bf16_t* xn   = (bf16_t*)(ws + 24 * MB);   // 4096x1024 bf16
    bf16_t* QKV  = (bf16_t*)(ws + 32 * MB);   // 4096x3072 bf16 (24 MB)
    bf16_t* att  = (bf16_t*)(ws + 56 * MB);   // 4096x1024 bf16
    float*  x1   = (float*)(ws + 64 * MB);    // 4096x1024 fp32 (16 MB)
    bf16_t* hb   = (bf16_t*)(ws + 80 * MB);   // 4096x1024 bf16
    bf16_t* h1   = (bf16_t*)(ws + 88 * MB);   // 4096x4096 bf16 (32 MB)
    bf16_t* Vtb  = (bf16_t*)(ws + 88 * MB);   // 8 MB alias; dead before h1 write

    dim3 blk(256);

    transpose_cvt<<<dim3(E_ / 32, E_ / 32), blk, 0, stream>>>(Wq, wqkv, E_, E_);
    transpose_cvt<<<dim3(E_ / 32, E_ / 32), blk, 0, stream>>>(Wk, wqkv + (size_t)E_ * E_, E_, E_);
    transpose_cvt<<<dim3(E_ / 32, E_ / 32), blk, 0, stream>>>(Wv, wqkv + (size_t)2 * E_ * E_, E_, E_);
    transpose_cvt<<<dim3(E_ / 32, E_ / 32), blk, 0, stream>>>(Wo, wot, E_, E_);
    transpose_cvt<<<dim3(FF_ / 32, E_ / 32), blk, 0, stream>>>(W1, w1t, E_, FF_);
    transpose_cvt<<<dim3(E_ / 32, FF_ / 32), blk, 0, stream>>>(W2, w2t, FF_, E_);

    ln_kernel<<<dim3(NROW), blk, 0, stream>>>(x, ln1g, ln1b, xn);

    // fused QKV projection: C[4096][3072]
    gemm_bt<<<dim3(NROW / BM, QS_ / BN), blk, 0, stream>>>(
        xn, wqkv, nullptr, nullptr, QKV, NROW, QS_, E_, 0, 0, 0, 1);

    // V -> per-head transposed layout
    vt_kernel<<<dim3(T_ / 32, B_ * H_), blk, 0, stream>>>(QKV + 2 * E_, Vtb);

    // balanced MFMA flash attention (paired q-tiles)
    attn_mfma<<<dim3(T_ / 128, B_ * H_), blk, 0, stream>>>(
        QKV, QKV + E_, Vtb, att);

    gemm_bt<<<dim3(NROW / BM, E_ / BN), blk, 0, stream>>>(
        att, wot, bo, x, x1, NROW, E_, E_, 1, 0, 1, 0);

    ln_kernel<<<dim3(NROW), blk, 0, stream>>>(x1, ln2g, ln2b, hb);

    gemm_bt<<<dim3(NROW / BM, FF_ / BN), blk, 0, stream>>>(
        hb, w1t, b1, nullptr, h1, NROW, FF_, E_, 1, 1, 0, 1);

    gemm_bt<<<dim3(NROW / BM, E_ / BN), blk, 0, stream>>>(
        h1, w2t, b2, x1, (float*)d_out, NROW, E_, FF_, 1, 0, 1, 0);
}

// Round 4
// 426.385 us; speedup vs baseline: 3.0716x; 1.1053x over previous
//
#include <hip/hip_runtime.h>
#include <cmath>
#include <cstdint>
#include <cstddef>

typedef __bf16 bf16_t;
typedef __bf16 bf16x8 __attribute__((ext_vector_type(8)));
typedef float  f32x4  __attribute__((ext_vector_type(4)));

#define B_   2
#define T_   2048
#define E_   1024
#define H_   16
#define D_   64
#define FF_  4096
#define NROW (B_ * T_)   // 4096
#define QS_  (3 * E_)    // packed QKV row stride

// async global->LDS, 16B per lane (m97 pattern)
__device__ __forceinline__ void gll16(const bf16_t* g, bf16_t* l) {
    __builtin_amdgcn_global_load_lds(
        (const __attribute__((address_space(1))) unsigned int*)g,
        (__attribute__((address_space(3))) unsigned int*)l, 16, 0, 0);
}

// ---------------------------------------------------------------- LN ----
__global__ __launch_bounds__(256) void ln_kernel(
    const float* __restrict__ x, const float* __restrict__ g,
    const float* __restrict__ bta, bf16_t* __restrict__ out)
{
    int row = blockIdx.x;
    int tid = threadIdx.x;
    const float4* xr = (const float4*)(x + (size_t)row * E_);
    float4 v = xr[tid];
    float s  = v.x + v.y + v.z + v.w;
    float ss = v.x * v.x + v.y * v.y + v.z * v.z + v.w * v.w;
#pragma unroll
    for (int off = 32; off; off >>= 1) {
        s  += __shfl_xor(s, off);
        ss += __shfl_xor(ss, off);
    }
    __shared__ float red[8];
    int wave = tid >> 6, lane = tid & 63;
    if (lane == 0) { red[wave] = s; red[4 + wave] = ss; }
    __syncthreads();
    s  = red[0] + red[1] + red[2] + red[3];
    ss = red[4] + red[5] + red[6] + red[7];
    float mu   = s * (1.0f / E_);
    float var  = ss * (1.0f / E_) - mu * mu;
    float rstd = rsqrtf(var + 1e-5f);
    float4 gv = ((const float4*)g)[tid];
    float4 bv = ((const float4*)bta)[tid];
    union { bf16_t h[4]; ushort4 u; } pk;
    pk.h[0] = (bf16_t)((v.x - mu) * rstd * gv.x + bv.x);
    pk.h[1] = (bf16_t)((v.y - mu) * rstd * gv.y + bv.y);
    pk.h[2] = (bf16_t)((v.z - mu) * rstd * gv.z + bv.z);
    pk.h[3] = (bf16_t)((v.w - mu) * rstd * gv.w + bv.w);
    ((ushort4*)(out + (size_t)row * E_))[tid] = pk.u;
}

// ---------------- split-K reduce (2 slices) + bias + resid + LN --------
// One block per row. x1 = p0 + p1 + bias + resid; out = LN(x1)*g + b.
__global__ __launch_bounds__(256) void ln_reduce2(
    const float* __restrict__ p, const float* __restrict__ bias,
    const float* __restrict__ resid, float* __restrict__ x1,
    const float* __restrict__ g, const float* __restrict__ bta,
    bf16_t* __restrict__ out)
{
    int row = blockIdx.x;
    int tid = threadIdx.x;
    size_t off = (size_t)row * E_;
    float4 v0 = ((const float4*)(p + off))[tid];
    float4 v1 = ((const float4*)(p + (size_t)NROW * E_ + off))[tid];
    float4 bb = ((const float4*)bias)[tid];
    float4 rr = ((const float4*)(resid + off))[tid];
    float4 v;
    v.x = v0.x + v1.x + bb.x + rr.x;
    v.y = v0.y + v1.y + bb.y + rr.y;
    v.z = v0.z + v1.z + bb.z + rr.z;
    v.w = v0.w + v1.w + bb.w + rr.w;
    ((float4*)(x1 + off))[tid] = v;
    float s  = v.x + v.y + v.z + v.w;
    float ss = v.x * v.x + v.y * v.y + v.z * v.z + v.w * v.w;
#pragma unroll
    for (int o = 32; o; o >>= 1) {
        s  += __shfl_xor(s, o);
        ss += __shfl_xor(ss, o);
    }
    __shared__ float red[8];
    int wave = tid >> 6, lane = tid & 63;
    if (lane == 0) { red[wave] = s; red[4 + wave] = ss; }
    __syncthreads();
    s  = red[0] + red[1] + red[2] + red[3];
    ss = red[4] + red[5] + red[6] + red[7];
    float mu   = s * (1.0f / E_);
    float var  = ss * (1.0f / E_) - mu * mu;
    float rstd = rsqrtf(var + 1e-5f);
    float4 gv = ((const float4*)g)[tid];
    float4 bv = ((const float4*)bta)[tid];
    union { bf16_t h[4]; ushort4 u; } pk;
    pk.h[0] = (bf16_t)((v.x - mu) * rstd * gv.x + bv.x);
    pk.h[1] = (bf16_t)((v.y - mu) * rstd * gv.y + bv.y);
    pk.h[2] = (bf16_t)((v.z - mu) * rstd * gv.z + bv.z);
    pk.h[3] = (bf16_t)((v.w - mu) * rstd * gv.w + bv.w);
    ((ushort4*)(out + off))[tid] = pk.u;
}

// ---------------- split-K reduce (2 slices) + bias + resid -> fp32 -----
__global__ __launch_bounds__(256) void add_reduce2(
    const float* __restrict__ p, const float* __restrict__ bias,
    const float* __restrict__ resid, float* __restrict__ out)
{
    int row = blockIdx.x;
    int tid = threadIdx.x;
    size_t off = (size_t)row * E_;
    float4 v0 = ((const float4*)(p + off))[tid];
    float4 v1 = ((const float4*)(p + (size_t)NROW * E_ + off))[tid];
    float4 bb = ((const float4*)bias)[tid];
    float4 rr = ((const float4*)(resid + off))[tid];
    float4 v;
    v.x = v0.x + v1.x + bb.x + rr.x;
    v.y = v0.y + v1.y + bb.y + rr.y;
    v.z = v0.z + v1.z + bb.z + rr.z;
    v.w = v0.w + v1.w + bb.w + rr.w;
    ((float4*)(out + off))[tid] = v;
}

// -------------------------------------------- weight transpose + cvt ----
__global__ __launch_bounds__(256) void transpose_cvt(
    const float* __restrict__ W, bf16_t* __restrict__ Wt, int K, int N)
{
    __shared__ float t[32][33];
    int n0 = blockIdx.x * 32, k0 = blockIdx.y * 32;
    int tx = threadIdx.x & 31, ty = threadIdx.x >> 5;
#pragma unroll
    for (int i = 0; i < 4; ++i)
        t[ty + i * 8][tx] = W[(size_t)(k0 + ty + i * 8) * N + n0 + tx];
    __syncthreads();
#pragma unroll
    for (int i = 0; i < 4; ++i)
        Wt[(size_t)(n0 + ty + i * 8) * K + k0 + tx] = (bf16_t)t[tx][ty + i * 8];
}

// --------------------------------------------- V transpose (per head) ---
__global__ __launch_bounds__(256) void vt_kernel(
    const bf16_t* __restrict__ V, bf16_t* __restrict__ Vt)
{
    int wave = threadIdx.x >> 6, lane = threadIdx.x & 63;
    int bh = blockIdx.y, b = bh >> 4, h = bh & 15;
    int t0 = blockIdx.x * 32 + wave * 8;
    const unsigned short* src =
        (const unsigned short*)V + (size_t)(b * T_ + t0) * QS_ + h * D_ + lane;
    unsigned short vals[8];
#pragma unroll
    for (int j = 0; j < 8; ++j) vals[j] = src[(size_t)j * QS_];
    unsigned short* dst =
        (unsigned short*)Vt + ((size_t)bh * D_ + lane) * T_ + t0;
    *(uint4*)dst = *(uint4*)vals;
}

// ----------------------------------------------------------- GEMM ------
// m97 structure + optional split-K via blockIdx.z (slice length = K arg;
// partials to fp32 [z][M][N], bias/relu/resid skipped when gridDim.z>1).
#define BM 128
#define BN 128
#define BK 32

__global__ __launch_bounds__(256) void gemm_bt(
    const bf16_t* __restrict__ A, const bf16_t* __restrict__ Bt,
    const float* __restrict__ bias, const float* __restrict__ resid,
    void* __restrict__ Cout, int M, int N, int K, int lda, int ldb,
    int has_bias, int do_relu, int has_resid, int out_bf16)
{
    __shared__ __attribute__((aligned(16))) bf16_t As[BM * BK];
    __shared__ __attribute__((aligned(16))) bf16_t Bs[BN * BK];
    int tid  = threadIdx.x;
    int lane = tid & 63, wave = tid >> 6;
    int m0 = blockIdx.x * BM, n0 = blockIdx.y * BN;
    int wm = (wave & 1) * 64, wn = (wave >> 1) * 64;
    int koff = blockIdx.z * K;
    f32x4 acc[4][4];
#pragma unroll
    for (int i = 0; i < 4; ++i)
#pragma unroll
        for (int j = 0; j < 4; ++j) acc[i][j] = (f32x4){0.f, 0.f, 0.f, 0.f};

    int sr = tid >> 2;            // 0..63
    int sc = (tid & 3) * 8;       // 0,8,16,24
    const int kq = (lane >> 4) * 8;
    const int ml = lane & 15;
    const bf16_t* Ag = A  + (size_t)(m0 + sr) * lda + koff + sc;
    const bf16_t* Bg = Bt + (size_t)(n0 + sr) * ldb + koff + sc;
    bf16_t* Al = &As[sr * BK + sc];
    bf16_t* Bl = &Bs[sr * BK + sc];

    for (int k0 = 0; k0 < K; k0 += BK) {
        gll16(Ag + k0, Al);
        gll16(Ag + k0 + (size_t)64 * lda, Al + 64 * BK);
        gll16(Bg + k0, Bl);
        gll16(Bg + k0 + (size_t)64 * ldb, Bl + 64 * BK);
        __syncthreads();   // drains vmcnt (data ready)
        bf16x8 af[4], bfr[4];
#pragma unroll
        for (int mi = 0; mi < 4; ++mi)
            af[mi] = *(const bf16x8*)&As[(wm + mi * 16 + ml) * BK + kq];
#pragma unroll
        for (int ni = 0; ni < 4; ++ni)
            bfr[ni] = *(const bf16x8*)&Bs[(wn + ni * 16 + ml) * BK + kq];
#pragma unroll
        for (int mi = 0; mi < 4; ++mi)
#pragma unroll
            for (int ni = 0; ni < 4; ++ni)
                acc[mi][ni] = __builtin_amdgcn_mfma_f32_16x16x32_bf16(
                    af[mi], bfr[ni], acc[mi][ni], 0, 0, 0);
        __syncthreads();   // WAR before next stage
    }

    int r4 = (lane >> 4) * 4;
    if (gridDim.z > 1) {
        // split-K partial: raw fp32, no epilogue
        float* P = (float*)Cout + (size_t)blockIdx.z * M * N;
#pragma unroll
        for (int mi = 0; mi < 4; ++mi)
#pragma unroll
            for (int ni = 0; ni < 4; ++ni) {
                int col = n0 + wn + ni * 16 + ml;
#pragma unroll
                for (int r = 0; r < 4; ++r) {
                    int row = m0 + wm + mi * 16 + r4 + r;
                    P[(size_t)row * N + col] = acc[mi][ni][r];
                }
            }
        return;
    }
#pragma unroll
    for (int mi = 0; mi < 4; ++mi) {
#pragma unroll
        for (int ni = 0; ni < 4; ++ni) {
            int col = n0 + wn + ni * 16 + ml;
            float bval = has_bias ? bias[col] : 0.0f;
#pragma unroll
            for (int r = 0; r < 4; ++r) {
                int row = m0 + wm + mi * 16 + r4 + r;
                float v = acc[mi][ni][r] + bval;
                if (do_relu)   v = fmaxf(v, 0.0f);
                if (has_resid) v += resid[(size_t)row * N + col];
                if (out_bf16)
                    ((bf16_t*)Cout)[(size_t)row * N + col] = (bf16_t)v;
                else
                    ((float*)Cout)[(size_t)row * N + col] = v;
            }
        }
    }
}

// ------------------------------------------------- MFMA flash attention -
#define PSTR 72

__global__ __launch_bounds__(256) void attn_mfma(
    const bf16_t* __restrict__ Qp, const bf16_t* __restrict__ Kp,
    const bf16_t* __restrict__ Vt, bf16_t* __restrict__ O)
{
    __shared__ __attribute__((aligned(16))) bf16_t Ks[64 * PSTR];   // [key][d]
    __shared__ __attribute__((aligned(16))) bf16_t Vts[64 * PSTR];  // [d][key]
    __shared__ __attribute__((aligned(16))) bf16_t Ps[4][16 * PSTR];

    int tid = threadIdx.x, lane = tid & 63, wave = tid >> 6;
    int ml  = lane & 15;
    int kq8 = (lane >> 4) * 8;
    int r4  = (lane >> 4) * 4;
    int bh = blockIdx.y, b = bh >> 4, h = bh & 15;
    size_t qk_base = (size_t)b * T_ * QS_ + h * D_;
    size_t vt_base = (size_t)bh * D_ * T_;
    size_t o_base  = (size_t)b * T_ * E_ + h * D_;
    const int NT = T_ / 64;

    for (int rep = 0; rep < 2; ++rep) {
        int tile = rep ? (NT - 1 - blockIdx.x) : blockIdx.x;
        int q0 = tile * 64;
        int qw = q0 + wave * 16;

        bf16x8 qf[2];
#pragma unroll
        for (int ks = 0; ks < 2; ++ks) {
            bf16x8 raw = *(const bf16x8*)&Qp[qk_base + (size_t)(qw + ml) * QS_ + ks * 32 + kq8];
#pragma unroll
            for (int j = 0; j < 8; ++j) raw[j] = (bf16_t)((float)raw[j] * 0.125f);
            qf[ks] = raw;
        }

        f32x4 acc[4];
#pragma unroll
        for (int dt = 0; dt < 4; ++dt) acc[dt] = (f32x4){0.f, 0.f, 0.f, 0.f};
        float m1 = -INFINITY, l1 = 0.f;

        int nch = q0 / 64 + 1;
        for (int ch = 0; ch < nch; ++ch) {
            __syncthreads();   // WAR on Ks/Vts
#pragma unroll
            for (int i = 0; i < 2; ++i) {
                int v = tid + i * 256;
                int r = v >> 3, c = (v & 7) * 8;
                *(uint4*)&Ks[r * PSTR + c] =
                    *(const uint4*)&Kp[qk_base + (size_t)(ch * 64 + r) * QS_ + c];
                *(uint4*)&Vts[r * PSTR + c] =
                    *(const uint4*)&Vt[vt_base + (size_t)r * T_ + ch * 64 + c];
            }
            __syncthreads();

            // S^T = K Q^T
            f32x4 s[4];
#pragma unroll
            for (int nt = 0; nt < 4; ++nt) {
                s[nt] = (f32x4){0.f, 0.f, 0.f, 0.f};
#pragma unroll
                for (int ks = 0; ks < 2; ++ks) {
                    bf16x8 kf = *(const bf16x8*)&Ks[(nt * 16 + ml) * PSTR + ks * 32 + kq8];
                    s[nt] = __builtin_amdgcn_mfma_f32_16x16x32_bf16(kf, qf[ks], s[nt], 0, 0, 0);
                }
            }

            if (ch == nch - 1) {
                int q = qw + ml;
#pragma unroll
                for (int nt = 0; nt < 4; ++nt)
#pragma unroll
                    for (int r = 0; r < 4; ++r)
                        if (ch * 64 + nt * 16 + r4 + r > q) s[nt][r] = -INFINITY;
            }

            float mx = -INFINITY;
#pragma unroll
            for (int nt = 0; nt < 4; ++nt)
#pragma unroll
                for (int r = 0; r < 4; ++r) mx = fmaxf(mx, s[nt][r]);
            mx = fmaxf(mx, __shfl_xor(mx, 16));
            mx = fmaxf(mx, __shfl_xor(mx, 32));
            float mn = fmaxf(m1, mx);
            float al = __expf(m1 - mn);
            m1 = mn;
            float sum = 0.f;
#pragma unroll
            for (int nt = 0; nt < 4; ++nt)
#pragma unroll
                for (int r = 0; r < 4; ++r) {
                    float p = __expf(s[nt][r] - mn);
                    s[nt][r] = p;
                    sum += p;
                }
            sum += __shfl_xor(sum, 16);
            sum += __shfl_xor(sum, 32);
            l1 = l1 * al + sum;
#pragma unroll
            for (int dt = 0; dt < 4; ++dt)
#pragma unroll
                for (int r = 0; r < 4; ++r) acc[dt][r] *= al;

#pragma unroll
            for (int nt = 0; nt < 4; ++nt) {
                union { bf16_t h[4]; uint2 u; } pk;
#pragma unroll
                for (int r = 0; r < 4; ++r) pk.h[r] = (bf16_t)s[nt][r];
                *(uint2*)&Ps[wave][ml * PSTR + nt * 16 + r4] = pk.u;
            }

            // O^T += V^T P^T
#pragma unroll
            for (int ks = 0; ks < 2; ++ks) {
                bf16x8 pf = *(const bf16x8*)&Ps[wave][ml * PSTR + ks * 32 + kq8];
#pragma unroll
                for (int dt = 0; dt < 4; ++dt) {
                    bf16x8 vf = *(const bf16x8*)&Vts[(dt * 16 + ml) * PSTR + ks * 32 + kq8];
                    acc[dt] = __builtin_amdgcn_mfma_f32_16x16x32_bf16(vf, pf, acc[dt], 0, 0, 0);
                }
            }
        }

        float inv = 1.0f / l1;
#pragma unroll
        for (int dt = 0; dt < 4; ++dt) {
            union { bf16_t h[4]; uint2 u; } pk;
#pragma unroll
            for (int r = 0; r < 4; ++r) pk.h[r] = (bf16_t)(acc[dt][r] * inv);
            *(uint2*)&Ps[wave][ml * PSTR + dt * 16 + r4] = pk.u;
        }
        {
            int row = lane >> 2, seg = (lane & 3) * 16;
            bf16x8 o0 = *(const bf16x8*)&Ps[wave][row * PSTR + seg];
            bf16x8 o1 = *(const bf16x8*)&Ps[wave][row * PSTR + seg + 8];
            size_t g = o_base + (size_t)(qw + row) * E_ + seg;
            *(bf16x8*)&O[g]     = o0;
            *(bf16x8*)&O[g + 8] = o1;
        }
    }
}

// ------------------------------------------------------------ launch ---
extern "C" void kernel_launch(void* const* d_in, const int* in_sizes, int n_in,
                              void* d_out, int out_size, void* d_ws, size_t ws_size,
                              hipStream_t stream)
{
    const float* x    = (const float*)d_in[0];
    const float* ln1g = (const float*)d_in[1];
    const float* ln1b = (const float*)d_in[2];
    const float* Wq   = (const float*)d_in[3];
    const float* Wk   = (const float*)d_in[4];
    const float* Wv   = (const float*)d_in[5];
    const float* Wo   = (const float*)d_in[6];
    const float* bo   = (const float*)d_in[7];
    const float* ln2g = (const float*)d_in[8];
    const float* ln2b = (const float*)d_in[9];
    const float* W1   = (const float*)d_in[10];
    const float* b1   = (const float*)d_in[11];
    const float* W2   = (const float*)d_in[12];
    const float* b2   = (const float*)d_in[13];

    char* ws = (char*)d_ws;
    const size_t MB = 1024ull * 1024ull;
    bf16_t* wqkv = (bf16_t*)(ws + 0 * MB);    // 3072x1024 bf16 (6 MB)
    bf16_t* wot  = (bf16_t*)(ws + 6 * MB);    // 1024x1024 bf16
    bf16_t* w1t  = (bf16_t*)(ws + 8 * MB);    // 4096x1024 bf16
    bf16_t* w2t  = (bf16_t*)(ws + 16 * MB);   // 1024x4096 bf16
    bf16_t* xn   = (bf16_t*)(ws + 24 * MB);   // 4096x1024 bf16 (dead after QKV)
    bf16_t* QKV  = (bf16_t*)(ws + 32 * MB);   // 4096x3072 bf16 (dead after attn)
    bf16_t* att  = (bf16_t*)(ws + 56 * MB);   // 4096x1024 bf16 (dead after Wo)
    float*  x1   = (float*)(ws + 64 * MB);    // 4096x1024 fp32
    bf16_t* hb   = (bf16_t*)(ws + 80 * MB);   // 4096x1024 bf16
    bf16_t* h1   = (bf16_t*)(ws + 88 * MB);   // 4096x4096 bf16 (32 MB)
    bf16_t* Vtb  = (bf16_t*)(ws + 88 * MB);   // 8 MB alias; dead before h1 write
    float*  part = (float*)(ws + 24 * MB);    // 2x16 MB fp32 split-K partials
                                              // (xn/QKV dead when Wo runs;
                                              //  Wo partials dead when MLP-down runs)

    dim3 blk(256);

    transpose_cvt<<<dim3(E_ / 32, E_ / 32), blk, 0, stream>>>(Wq, wqkv, E_, E_);
    transpose_cvt<<<dim3(E_ / 32, E_ / 32), blk, 0, stream>>>(Wk, wqkv + (size_t)E_ * E_, E_, E_);
    transpose_cvt<<<dim3(E_ / 32, E_ / 32), blk, 0, stream>>>(Wv, wqkv + (size_t)2 * E_ * E_, E_, E_);
    transpose_cvt<<<dim3(E_ / 32, E_ / 32), blk, 0, stream>>>(Wo, wot, E_, E_);
    transpose_cvt<<<dim3(FF_ / 32, E_ / 32), blk, 0, stream>>>(W1, w1t, E_, FF_);
    transpose_cvt<<<dim3(E_ / 32, FF_ / 32), blk, 0, stream>>>(W2, w2t, FF_, E_);

    ln_kernel<<<dim3(NROW), blk, 0, stream>>>(x, ln1g, ln1b, xn);

    // fused QKV projection: C[4096][3072]  (768 blocks, 3/CU)
    gemm_bt<<<dim3(NROW / BM, QS_ / BN), blk, 0, stream>>>(
        xn, wqkv, nullptr, nullptr, QKV, NROW, QS_, E_, E_, E_, 0, 0, 0, 1);

    vt_kernel<<<dim3(T_ / 32, B_ * H_), blk, 0, stream>>>(QKV + 2 * E_, Vtb);

    attn_mfma<<<dim3(T_ / 128, B_ * H_), blk, 0, stream>>>(
        QKV, QKV + E_, Vtb, att);

    // Wo projection: split-K x2 (512 blocks), partials -> reduce+LN2 fused
    gemm_bt<<<dim3(NROW / BM, E_ / BN, 2), blk, 0, stream>>>(
        att, wot, nullptr, nullptr, part, NROW, E_, E_ / 2, E_, E_, 0, 0, 0, 0);
    ln_reduce2<<<dim3(NROW), blk, 0, stream>>>(
        part, bo, x, x1, ln2g, ln2b, hb);

    // MLP up + bias + relu -> h1 (1024 blocks, 4/CU)
    gemm_bt<<<dim3(NROW / BM, FF_ / BN), blk, 0, stream>>>(
        hb, w1t, b1, nullptr, h1, NROW, FF_, E_, E_, E_, 1, 1, 0, 1);

    // MLP down: split-K x2 (512 blocks), partials -> reduce + b2 + resid
    gemm_bt<<<dim3(NROW / BM, E_ / BN, 2), blk, 0, stream>>>(
        h1, w2t, nullptr, nullptr, part, NROW, E_, FF_ / 2, FF_, FF_, 0, 0, 0, 0);
    add_reduce2<<<dim3(NROW), blk, 0, stream>>>(
        part, b2, x1, (float*)d_out);
}

// Round 5
// 393.105 us; speedup vs baseline: 3.3317x; 1.0847x over previous
//
#include <hip/hip_runtime.h>
#include <cmath>
#include <cstdint>
#include <cstddef>

typedef __bf16 bf16_t;
typedef __bf16 bf16x8 __attribute__((ext_vector_type(8)));
typedef float  f32x4  __attribute__((ext_vector_type(4)));

#define B_   2
#define T_   2048
#define E_   1024
#define H_   16
#define D_   64
#define FF_  4096
#define NROW (B_ * T_)   // 4096
#define QS_  (3 * E_)    // packed QKV row stride
#define NTI  (T_ / 64)   // 32 q-tiles

// async global->LDS, 16B per lane (m97 pattern)
__device__ __forceinline__ void gll16(const bf16_t* g, bf16_t* l) {
    __builtin_amdgcn_global_load_lds(
        (const __attribute__((address_space(1))) unsigned int*)g,
        (__attribute__((address_space(3))) unsigned int*)l, 16, 0, 0);
}

// ---------------------------------------------------------------- LN ----
__global__ __launch_bounds__(256) void ln_kernel(
    const float* __restrict__ x, const float* __restrict__ g,
    const float* __restrict__ bta, bf16_t* __restrict__ out)
{
    int row = blockIdx.x;
    int tid = threadIdx.x;
    const float4* xr = (const float4*)(x + (size_t)row * E_);
    float4 v = xr[tid];
    float s  = v.x + v.y + v.z + v.w;
    float ss = v.x * v.x + v.y * v.y + v.z * v.z + v.w * v.w;
#pragma unroll
    for (int off = 32; off; off >>= 1) {
        s  += __shfl_xor(s, off);
        ss += __shfl_xor(ss, off);
    }
    __shared__ float red[8];
    int wave = tid >> 6, lane = tid & 63;
    if (lane == 0) { red[wave] = s; red[4 + wave] = ss; }
    __syncthreads();
    s  = red[0] + red[1] + red[2] + red[3];
    ss = red[4] + red[5] + red[6] + red[7];
    float mu   = s * (1.0f / E_);
    float var  = ss * (1.0f / E_) - mu * mu;
    float rstd = rsqrtf(var + 1e-5f);
    float4 gv = ((const float4*)g)[tid];
    float4 bv = ((const float4*)bta)[tid];
    union { bf16_t h[4]; ushort4 u; } pk;
    pk.h[0] = (bf16_t)((v.x - mu) * rstd * gv.x + bv.x);
    pk.h[1] = (bf16_t)((v.y - mu) * rstd * gv.y + bv.y);
    pk.h[2] = (bf16_t)((v.z - mu) * rstd * gv.z + bv.z);
    pk.h[3] = (bf16_t)((v.w - mu) * rstd * gv.w + bv.w);
    ((ushort4*)(out + (size_t)row * E_))[tid] = pk.u;
}

// ---------------- split-K reduce (2 slices) + bias + resid + LN --------
__global__ __launch_bounds__(256) void ln_reduce2(
    const float* __restrict__ p, const float* __restrict__ bias,
    const float* __restrict__ resid, float* __restrict__ x1,
    const float* __restrict__ g, const float* __restrict__ bta,
    bf16_t* __restrict__ out)
{
    int row = blockIdx.x;
    int tid = threadIdx.x;
    size_t off = (size_t)row * E_;
    float4 v0 = ((const float4*)(p + off))[tid];
    float4 v1 = ((const float4*)(p + (size_t)NROW * E_ + off))[tid];
    float4 bb = ((const float4*)bias)[tid];
    float4 rr = ((const float4*)(resid + off))[tid];
    float4 v;
    v.x = v0.x + v1.x + bb.x + rr.x;
    v.y = v0.y + v1.y + bb.y + rr.y;
    v.z = v0.z + v1.z + bb.z + rr.z;
    v.w = v0.w + v1.w + bb.w + rr.w;
    ((float4*)(x1 + off))[tid] = v;
    float s  = v.x + v.y + v.z + v.w;
    float ss = v.x * v.x + v.y * v.y + v.z * v.z + v.w * v.w;
#pragma unroll
    for (int o = 32; o; o >>= 1) {
        s  += __shfl_xor(s, o);
        ss += __shfl_xor(ss, o);
    }
    __shared__ float red[8];
    int wave = tid >> 6, lane = tid & 63;
    if (lane == 0) { red[wave] = s; red[4 + wave] = ss; }
    __syncthreads();
    s  = red[0] + red[1] + red[2] + red[3];
    ss = red[4] + red[5] + red[6] + red[7];
    float mu   = s * (1.0f / E_);
    float var  = ss * (1.0f / E_) - mu * mu;
    float rstd = rsqrtf(var + 1e-5f);
    float4 gv = ((const float4*)g)[tid];
    float4 bv = ((const float4*)bta)[tid];
    union { bf16_t h[4]; ushort4 u; } pk;
    pk.h[0] = (bf16_t)((v.x - mu) * rstd * gv.x + bv.x);
    pk.h[1] = (bf16_t)((v.y - mu) * rstd * gv.y + bv.y);
    pk.h[2] = (bf16_t)((v.z - mu) * rstd * gv.z + bv.z);
    pk.h[3] = (bf16_t)((v.w - mu) * rstd * gv.w + bv.w);
    ((ushort4*)(out + off))[tid] = pk.u;
}

// ---------------- split-K reduce (2 slices) + bias + resid -> fp32 -----
__global__ __launch_bounds__(256) void add_reduce2(
    const float* __restrict__ p, const float* __restrict__ bias,
    const float* __restrict__ resid, float* __restrict__ out)
{
    int row = blockIdx.x;
    int tid = threadIdx.x;
    size_t off = (size_t)row * E_;
    float4 v0 = ((const float4*)(p + off))[tid];
    float4 v1 = ((const float4*)(p + (size_t)NROW * E_ + off))[tid];
    float4 bb = ((const float4*)bias)[tid];
    float4 rr = ((const float4*)(resid + off))[tid];
    float4 v;
    v.x = v0.x + v1.x + bb.x + rr.x;
    v.y = v0.y + v1.y + bb.y + rr.y;
    v.z = v0.z + v1.z + bb.z + rr.z;
    v.w = v0.w + v1.w + bb.w + rr.w;
    ((float4*)(out + off))[tid] = v;
}

// -------------------------------------------- weight transpose + cvt ----
__global__ __launch_bounds__(256) void transpose_cvt(
    const float* __restrict__ W, bf16_t* __restrict__ Wt, int K, int N)
{
    __shared__ float t[32][33];
    int n0 = blockIdx.x * 32, k0 = blockIdx.y * 32;
    int tx = threadIdx.x & 31, ty = threadIdx.x >> 5;
#pragma unroll
    for (int i = 0; i < 4; ++i)
        t[ty + i * 8][tx] = W[(size_t)(k0 + ty + i * 8) * N + n0 + tx];
    __syncthreads();
#pragma unroll
    for (int i = 0; i < 4; ++i)
        Wt[(size_t)(n0 + ty + i * 8) * K + k0 + tx] = (bf16_t)t[tx][ty + i * 8];
}

// --------------------------------------------- V transpose (per head) ---
__global__ __launch_bounds__(256) void vt_kernel(
    const bf16_t* __restrict__ V, bf16_t* __restrict__ Vt)
{
    int wave = threadIdx.x >> 6, lane = threadIdx.x & 63;
    int bh = blockIdx.y, b = bh >> 4, h = bh & 15;
    int t0 = blockIdx.x * 32 + wave * 8;
    const unsigned short* src =
        (const unsigned short*)V + (size_t)(b * T_ + t0) * QS_ + h * D_ + lane;
    unsigned short vals[8];
#pragma unroll
    for (int j = 0; j < 8; ++j) vals[j] = src[(size_t)j * QS_];
    unsigned short* dst =
        (unsigned short*)Vt + ((size_t)bh * D_ + lane) * T_ + t0;
    *(uint4*)dst = *(uint4*)vals;
}

// ----------------------------------------------------------- GEMM ------
#define BM 128
#define BN 128
#define BK 32

__global__ __launch_bounds__(256) void gemm_bt(
    const bf16_t* __restrict__ A, const bf16_t* __restrict__ Bt,
    const float* __restrict__ bias, const float* __restrict__ resid,
    void* __restrict__ Cout, int M, int N, int K, int lda, int ldb,
    int has_bias, int do_relu, int has_resid, int out_bf16)
{
    __shared__ __attribute__((aligned(16))) bf16_t As[BM * BK];
    __shared__ __attribute__((aligned(16))) bf16_t Bs[BN * BK];
    int tid  = threadIdx.x;
    int lane = tid & 63, wave = tid >> 6;
    int m0 = blockIdx.x * BM, n0 = blockIdx.y * BN;
    int wm = (wave & 1) * 64, wn = (wave >> 1) * 64;
    int koff = blockIdx.z * K;
    f32x4 acc[4][4];
#pragma unroll
    for (int i = 0; i < 4; ++i)
#pragma unroll
        for (int j = 0; j < 4; ++j) acc[i][j] = (f32x4){0.f, 0.f, 0.f, 0.f};

    int sr = tid >> 2;
    int sc = (tid & 3) * 8;
    const int kq = (lane >> 4) * 8;
    const int ml = lane & 15;
    const bf16_t* Ag = A  + (size_t)(m0 + sr) * lda + koff + sc;
    const bf16_t* Bg = Bt + (size_t)(n0 + sr) * ldb + koff + sc;
    bf16_t* Al = &As[sr * BK + sc];
    bf16_t* Bl = &Bs[sr * BK + sc];

    for (int k0 = 0; k0 < K; k0 += BK) {
        gll16(Ag + k0, Al);
        gll16(Ag + k0 + (size_t)64 * lda, Al + 64 * BK);
        gll16(Bg + k0, Bl);
        gll16(Bg + k0 + (size_t)64 * ldb, Bl + 64 * BK);
        __syncthreads();
        bf16x8 af[4], bfr[4];
#pragma unroll
        for (int mi = 0; mi < 4; ++mi)
            af[mi] = *(const bf16x8*)&As[(wm + mi * 16 + ml) * BK + kq];
#pragma unroll
        for (int ni = 0; ni < 4; ++ni)
            bfr[ni] = *(const bf16x8*)&Bs[(wn + ni * 16 + ml) * BK + kq];
#pragma unroll
        for (int mi = 0; mi < 4; ++mi)
#pragma unroll
            for (int ni = 0; ni < 4; ++ni)
                acc[mi][ni] = __builtin_amdgcn_mfma_f32_16x16x32_bf16(
                    af[mi], bfr[ni], acc[mi][ni], 0, 0, 0);
        __syncthreads();
    }

    int r4 = (lane >> 4) * 4;
    if (gridDim.z > 1) {
        float* P = (float*)Cout + (size_t)blockIdx.z * M * N;
#pragma unroll
        for (int mi = 0; mi < 4; ++mi)
#pragma unroll
            for (int ni = 0; ni < 4; ++ni) {
                int col = n0 + wn + ni * 16 + ml;
#pragma unroll
                for (int r = 0; r < 4; ++r) {
                    int row = m0 + wm + mi * 16 + r4 + r;
                    P[(size_t)row * N + col] = acc[mi][ni][r];
                }
            }
        return;
    }
#pragma unroll
    for (int mi = 0; mi < 4; ++mi) {
#pragma unroll
        for (int ni = 0; ni < 4; ++ni) {
            int col = n0 + wn + ni * 16 + ml;
            float bval = has_bias ? bias[col] : 0.0f;
#pragma unroll
            for (int r = 0; r < 4; ++r) {
                int row = m0 + wm + mi * 16 + r4 + r;
                float v = acc[mi][ni][r] + bval;
                if (do_relu)   v = fmaxf(v, 0.0f);
                if (has_resid) v += resid[(size_t)row * N + col];
                if (out_bf16)
                    ((bf16_t*)Cout)[(size_t)row * N + col] = (bf16_t)v;
                else
                    ((float*)Cout)[(size_t)row * N + col] = v;
            }
        }
    }
}

// ------------------------------------------------- MFMA flash attention -
// Pair (i, NTI-1-i) share the chunk loop: K/V staged ONCE per chunk, both
// q-tiles computed on it (kf/vf LDS frags reused). Register double-buffered
// staging, ONE barrier per chunk: loads for ch+1 issue right after the
// barrier, land in VGPRs during compute, ds_write to the other LDS buffer
// at iteration end. Softmax state per-lane scalar (transposed orientation).
#define PSTR 72

struct TileState {
    f32x4 acc[4];
    float m1, l1;
};

// per-tile chunk update: S^T given kf, then online softmax + PV (reuses vf)
__device__ __forceinline__ void tile_update(
    const bf16x8 kf[2][4], const bf16x8 vf[2][4], const bf16x8 qf[2],
    TileState& st, bf16_t* PsW, int ml, int r4, int kq8,
    bool diag, int ch, int qrow)
{
    f32x4 s[4];
#pragma unroll
    for (int nt = 0; nt < 4; ++nt) {
        s[nt] = (f32x4){0.f, 0.f, 0.f, 0.f};
#pragma unroll
        for (int ks = 0; ks < 2; ++ks)
            s[nt] = __builtin_amdgcn_mfma_f32_16x16x32_bf16(kf[ks][nt], qf[ks], s[nt], 0, 0, 0);
    }
    if (diag) {
#pragma unroll
        for (int nt = 0; nt < 4; ++nt)
#pragma unroll
            for (int r = 0; r < 4; ++r)
                if (ch * 64 + nt * 16 + r4 + r > qrow) s[nt][r] = -INFINITY;
    }
    float mx = -INFINITY;
#pragma unroll
    for (int nt = 0; nt < 4; ++nt)
#pragma unroll
        for (int r = 0; r < 4; ++r) mx = fmaxf(mx, s[nt][r]);
    mx = fmaxf(mx, __shfl_xor(mx, 16));
    mx = fmaxf(mx, __shfl_xor(mx, 32));
    float mn = fmaxf(st.m1, mx);
    float al = __expf(st.m1 - mn);
    st.m1 = mn;
    float sum = 0.f;
#pragma unroll
    for (int nt = 0; nt < 4; ++nt)
#pragma unroll
        for (int r = 0; r < 4; ++r) {
            float p = __expf(s[nt][r] - mn);
            s[nt][r] = p;
            sum += p;
        }
    sum += __shfl_xor(sum, 16);
    sum += __shfl_xor(sum, 32);
    st.l1 = st.l1 * al + sum;
#pragma unroll
    for (int dt = 0; dt < 4; ++dt)
#pragma unroll
        for (int r = 0; r < 4; ++r) st.acc[dt][r] *= al;

    // P^T -> Ps[q][key] (wave-local, no barrier)
#pragma unroll
    for (int nt = 0; nt < 4; ++nt) {
        union { bf16_t h[4]; uint2 u; } pk;
#pragma unroll
        for (int r = 0; r < 4; ++r) pk.h[r] = (bf16_t)s[nt][r];
        *(uint2*)&PsW[ml * PSTR + nt * 16 + r4] = pk.u;
    }
#pragma unroll
    for (int ks = 0; ks < 2; ++ks) {
        bf16x8 pf = *(const bf16x8*)&PsW[ml * PSTR + ks * 32 + kq8];
#pragma unroll
        for (int dt = 0; dt < 4; ++dt)
            st.acc[dt] = __builtin_amdgcn_mfma_f32_16x16x32_bf16(vf[ks][dt], pf, st.acc[dt], 0, 0, 0);
    }
}

__global__ __launch_bounds__(256) void attn_mfma(
    const bf16_t* __restrict__ Qp, const bf16_t* __restrict__ Kp,
    const bf16_t* __restrict__ Vt, bf16_t* __restrict__ O)
{
    __shared__ __attribute__((aligned(16))) bf16_t Ks[2][64 * PSTR];
    __shared__ __attribute__((aligned(16))) bf16_t Vts[2][64 * PSTR];
    __shared__ __attribute__((aligned(16))) bf16_t Ps[4][16 * PSTR];

    int tid = threadIdx.x, lane = tid & 63, wave = tid >> 6;
    int ml  = lane & 15;
    int kq8 = (lane >> 4) * 8;
    int r4  = (lane >> 4) * 4;
    int bh = blockIdx.y, b = bh >> 4, h = bh & 15;
    size_t qk_base = (size_t)b * T_ * QS_ + h * D_;
    size_t vt_base = (size_t)bh * D_ * T_;
    size_t o_base  = (size_t)b * T_ * E_ + h * D_;

    int lo = blockIdx.x, hi = NTI - 1 - blockIdx.x;
    int qlo = lo * 64 + wave * 16;
    int qhi = hi * 64 + wave * 16;

    // Q fragments (B-operand), pre-scaled by 1/8 (exact in bf16)
    bf16x8 qfl[2], qfh[2];
#pragma unroll
    for (int ks = 0; ks < 2; ++ks) {
        bf16x8 a = *(const bf16x8*)&Qp[qk_base + (size_t)(qlo + ml) * QS_ + ks * 32 + kq8];
        bf16x8 c = *(const bf16x8*)&Qp[qk_base + (size_t)(qhi + ml) * QS_ + ks * 32 + kq8];
#pragma unroll
        for (int j = 0; j < 8; ++j) {
            a[j] = (bf16_t)((float)a[j] * 0.125f);
            c[j] = (bf16_t)((float)c[j] * 0.125f);
        }
        qfl[ks] = a; qfh[ks] = c;
    }

    TileState stl, sth;
#pragma unroll
    for (int dt = 0; dt < 4; ++dt) {
        stl.acc[dt] = (f32x4){0.f, 0.f, 0.f, 0.f};
        sth.acc[dt] = (f32x4){0.f, 0.f, 0.f, 0.f};
    }
    stl.m1 = -INFINITY; stl.l1 = 0.f;
    sth.m1 = -INFINITY; sth.l1 = 0.f;

    // staging coords: rows r0 and r0+32, col c0 (8 bf16 = 16 B)
    int r0 = tid >> 3, c0 = (tid & 7) * 8;
    int nch = hi + 1;

    // prologue: stage chunk 0 into buffer 0
    {
        const bf16_t* kb = &Kp[qk_base + (size_t)r0 * QS_ + c0];
        const bf16_t* vb = &Vt[vt_base + (size_t)r0 * T_ + c0];
        uint4 k0v = *(const uint4*)kb;
        uint4 k1v = *(const uint4*)(kb + (size_t)32 * QS_);
        uint4 v0v = *(const uint4*)vb;
        uint4 v1v = *(const uint4*)(vb + (size_t)32 * T_);
        *(uint4*)&Ks[0][r0 * PSTR + c0]         = k0v;
        *(uint4*)&Ks[0][(r0 + 32) * PSTR + c0]  = k1v;
        *(uint4*)&Vts[0][r0 * PSTR + c0]        = v0v;
        *(uint4*)&Vts[0][(r0 + 32) * PSTR + c0] = v1v;
    }

    for (int ch = 0; ch < nch; ++ch) {
        int cur = ch & 1, nxt = cur ^ 1;
        __syncthreads();   // buf[cur] ready; prev compute done (WAR for nxt)

        // issue next chunk's global loads (no wait — land during compute)
        uint4 nk0, nk1, nv0, nv1;
        bool pf = (ch + 1 < nch);
        if (pf) {
            const bf16_t* kb = &Kp[qk_base + (size_t)((ch + 1) * 64 + r0) * QS_ + c0];
            const bf16_t* vb = &Vt[vt_base + (size_t)r0 * T_ + (ch + 1) * 64 + c0];
            nk0 = *(const uint4*)kb;
            nk1 = *(const uint4*)(kb + (size_t)32 * QS_);
            nv0 = *(const uint4*)vb;
            nv1 = *(const uint4*)(vb + (size_t)32 * T_);
        }

        // K / V fragments (read once, reused by both tiles)
        bf16x8 kf[2][4], vf[2][4];
#pragma unroll
        for (int ks = 0; ks < 2; ++ks)
#pragma unroll
            for (int nt = 0; nt < 4; ++nt) {
                kf[ks][nt] = *(const bf16x8*)&Ks[cur][(nt * 16 + ml) * PSTR + ks * 32 + kq8];
                vf[ks][nt] = *(const bf16x8*)&Vts[cur][(nt * 16 + ml) * PSTR + ks * 32 + kq8];
            }

        // hi tile always active; lo tile while ch <= lo (block-uniform)
        tile_update(kf, vf, qfh, sth, Ps[wave], ml, r4, kq8,
                    ch == hi, ch, qhi + ml);
        if (ch <= lo)
            tile_update(kf, vf, qfl, stl, Ps[wave], ml, r4, kq8,
                        ch == lo, ch, qlo + ml);

        if (pf) {
            *(uint4*)&Ks[nxt][r0 * PSTR + c0]         = nk0;
            *(uint4*)&Ks[nxt][(r0 + 32) * PSTR + c0]  = nk1;
            *(uint4*)&Vts[nxt][r0 * PSTR + c0]        = nv0;
            *(uint4*)&Vts[nxt][(r0 + 32) * PSTR + c0] = nv1;
        }
    }

    // epilogue (wave-local): normalize, stage [q][d] in Ps, vector store
#pragma unroll
    for (int t = 0; t < 2; ++t) {
        TileState& st = t ? stl : sth;
        int qw = t ? qlo : qhi;
        float inv = 1.0f / st.l1;
#pragma unroll
        for (int dt = 0; dt < 4; ++dt) {
            union { bf16_t h[4]; uint2 u; } pk;
#pragma unroll
            for (int r = 0; r < 4; ++r) pk.h[r] = (bf16_t)(st.acc[dt][r] * inv);
            *(uint2*)&Ps[wave][ml * PSTR + dt * 16 + r4] = pk.u;
        }
        int row = lane >> 2, seg = (lane & 3) * 16;
        bf16x8 o0 = *(const bf16x8*)&Ps[wave][row * PSTR + seg];
        bf16x8 o1 = *(const bf16x8*)&Ps[wave][row * PSTR + seg + 8];
        size_t gp = o_base + (size_t)(qw + row) * E_ + seg;
        *(bf16x8*)&O[gp]     = o0;
        *(bf16x8*)&O[gp + 8] = o1;
    }
}

// ------------------------------------------------------------ launch ---
extern "C" void kernel_launch(void* const* d_in, const int* in_sizes, int n_in,
                              void* d_out, int out_size, void* d_ws, size_t ws_size,
                              hipStream_t stream)
{
    const float* x    = (const float*)d_in[0];
    const float* ln1g = (const float*)d_in[1];
    const float* ln1b = (const float*)d_in[2];
    const float* Wq   = (const float*)d_in[3];
    const float* Wk   = (const float*)d_in[4];
    const float* Wv   = (const float*)d_in[5];
    const float* Wo   = (const float*)d_in[6];
    const float* bo   = (const float*)d_in[7];
    const float* ln2g = (const float*)d_in[8];
    const float* ln2b = (const float*)d_in[9];
    const float* W1   = (const float*)d_in[10];
    const float* b1   = (const float*)d_in[11];
    const float* W2   = (const float*)d_in[12];
    const float* b2   = (const float*)d_in[13];

    char* ws = (char*)d_ws;
    const size_t MB = 1024ull * 1024ull;
    bf16_t* wqkv = (bf16_t*)(ws + 0 * MB);
    bf16_t* wot  = (bf16_t*)(ws + 6 * MB);
    bf16_t* w1t  = (bf16_t*)(ws + 8 * MB);
    bf16_t* w2t  = (bf16_t*)(ws + 16 * MB);
    bf16_t* xn   = (bf16_t*)(ws + 24 * MB);
    bf16_t* QKV  = (bf16_t*)(ws + 32 * MB);
    bf16_t* att  = (bf16_t*)(ws + 56 * MB);
    float*  x1   = (float*)(ws + 64 * MB);
    bf16_t* hb   = (bf16_t*)(ws + 80 * MB);
    bf16_t* h1   = (bf16_t*)(ws + 88 * MB);
    bf16_t* Vtb  = (bf16_t*)(ws + 88 * MB);  // 8 MB alias; dead before h1 write
    float*  part = (float*)(ws + 24 * MB);   // 2x16 MB split-K partials

    dim3 blk(256);

    transpose_cvt<<<dim3(E_ / 32, E_ / 32), blk, 0, stream>>>(Wq, wqkv, E_, E_);
    transpose_cvt<<<dim3(E_ / 32, E_ / 32), blk, 0, stream>>>(Wk, wqkv + (size_t)E_ * E_, E_, E_);
    transpose_cvt<<<dim3(E_ / 32, E_ / 32), blk, 0, stream>>>(Wv, wqkv + (size_t)2 * E_ * E_, E_, E_);
    transpose_cvt<<<dim3(E_ / 32, E_ / 32), blk, 0, stream>>>(Wo, wot, E_, E_);
    transpose_cvt<<<dim3(FF_ / 32, E_ / 32), blk, 0, stream>>>(W1, w1t, E_, FF_);
    transpose_cvt<<<dim3(E_ / 32, FF_ / 32), blk, 0, stream>>>(W2, w2t, FF_, E_);

    ln_kernel<<<dim3(NROW), blk, 0, stream>>>(x, ln1g, ln1b, xn);

    gemm_bt<<<dim3(NROW / BM, QS_ / BN), blk, 0, stream>>>(
        xn, wqkv, nullptr, nullptr, QKV, NROW, QS_, E_, E_, E_, 0, 0, 0, 1);

    vt_kernel<<<dim3(T_ / 32, B_ * H_), blk, 0, stream>>>(QKV + 2 * E_, Vtb);

    attn_mfma<<<dim3(NTI / 2, B_ * H_), blk, 0, stream>>>(
        QKV, QKV + E_, Vtb, att);

    gemm_bt<<<dim3(NROW / BM, E_ / BN, 2), blk, 0, stream>>>(
        att, wot, nullptr, nullptr, part, NROW, E_, E_ / 2, E_, E_, 0, 0, 0, 0);
    ln_reduce2<<<dim3(NROW), blk, 0, stream>>>(
        part, bo, x, x1, ln2g, ln2b, hb);

    gemm_bt<<<dim3(NROW / BM, FF_ / BN), blk, 0, stream>>>(
        hb, w1t, b1, nullptr, h1, NROW, FF_, E_, E_, E_, 1, 1, 0, 1);

    gemm_bt<<<dim3(NROW / BM, E_ / BN, 2), blk, 0, stream>>>(
        h1, w2t, nullptr, nullptr, part, NROW, E_, FF_ / 2, FF_, FF_, 0, 0, 0, 0);
    add_reduce2<<<dim3(NROW), blk, 0, stream>>>(
        part, b2, x1, (float*)d_out);
}

// Round 6
// 373.859 us; speedup vs baseline: 3.5032x; 1.0515x over previous
//
#include <hip/hip_runtime.h>
#include <cmath>
#include <cstdint>
#include <cstddef>

typedef __bf16 bf16_t;
typedef __bf16 bf16x8 __attribute__((ext_vector_type(8)));
typedef __bf16 bf16x4 __attribute__((ext_vector_type(4)));
typedef float  f32x4  __attribute__((ext_vector_type(4)));

#define B_   2
#define T_   2048
#define E_   1024
#define H_   16
#define D_   64
#define FF_  4096
#define NROW (B_ * T_)   // 4096
#define QS_  (3 * E_)    // packed QKV row stride
#define NTI  (T_ / 64)   // 32 q-tiles

// async global->LDS, 16B per lane (m97 pattern)
__device__ __forceinline__ void gll16(const bf16_t* g, bf16_t* l) {
    __builtin_amdgcn_global_load_lds(
        (const __attribute__((address_space(1))) unsigned int*)g,
        (__attribute__((address_space(3))) unsigned int*)l, 16, 0, 0);
}

// ---------------------------------------------------------------- LN ----
__global__ __launch_bounds__(256) void ln_kernel(
    const float* __restrict__ x, const float* __restrict__ g,
    const float* __restrict__ bta, bf16_t* __restrict__ out)
{
    int row = blockIdx.x;
    int tid = threadIdx.x;
    const float4* xr = (const float4*)(x + (size_t)row * E_);
    float4 v = xr[tid];
    float s  = v.x + v.y + v.z + v.w;
    float ss = v.x * v.x + v.y * v.y + v.z * v.z + v.w * v.w;
#pragma unroll
    for (int off = 32; off; off >>= 1) {
        s  += __shfl_xor(s, off);
        ss += __shfl_xor(ss, off);
    }
    __shared__ float red[8];
    int wave = tid >> 6, lane = tid & 63;
    if (lane == 0) { red[wave] = s; red[4 + wave] = ss; }
    __syncthreads();
    s  = red[0] + red[1] + red[2] + red[3];
    ss = red[4] + red[5] + red[6] + red[7];
    float mu   = s * (1.0f / E_);
    float var  = ss * (1.0f / E_) - mu * mu;
    float rstd = rsqrtf(var + 1e-5f);
    float4 gv = ((const float4*)g)[tid];
    float4 bv = ((const float4*)bta)[tid];
    union { bf16_t h[4]; ushort4 u; } pk;
    pk.h[0] = (bf16_t)((v.x - mu) * rstd * gv.x + bv.x);
    pk.h[1] = (bf16_t)((v.y - mu) * rstd * gv.y + bv.y);
    pk.h[2] = (bf16_t)((v.z - mu) * rstd * gv.z + bv.z);
    pk.h[3] = (bf16_t)((v.w - mu) * rstd * gv.w + bv.w);
    ((ushort4*)(out + (size_t)row * E_))[tid] = pk.u;
}

// ------------- split-K reduce (4 bf16 slices) + bias + resid + LN ------
__global__ __launch_bounds__(256) void ln_reduce4(
    const bf16_t* __restrict__ p, const float* __restrict__ bias,
    const float* __restrict__ resid, float* __restrict__ x1,
    const float* __restrict__ g, const float* __restrict__ bta,
    bf16_t* __restrict__ out)
{
    int row = blockIdx.x;
    int tid = threadIdx.x;
    size_t off = (size_t)row * E_ + tid * 4;
    float4 v = {0.f, 0.f, 0.f, 0.f};
#pragma unroll
    for (int z = 0; z < 4; ++z) {
        bf16x4 pv = *(const bf16x4*)&p[(size_t)z * NROW * E_ + off];
        v.x += (float)pv[0]; v.y += (float)pv[1];
        v.z += (float)pv[2]; v.w += (float)pv[3];
    }
    float4 bb = ((const float4*)bias)[tid];
    float4 rr = ((const float4*)(resid + (size_t)row * E_))[tid];
    v.x += bb.x + rr.x; v.y += bb.y + rr.y;
    v.z += bb.z + rr.z; v.w += bb.w + rr.w;
    ((float4*)(x1 + (size_t)row * E_))[tid] = v;
    float s  = v.x + v.y + v.z + v.w;
    float ss = v.x * v.x + v.y * v.y + v.z * v.z + v.w * v.w;
#pragma unroll
    for (int o = 32; o; o >>= 1) {
        s  += __shfl_xor(s, o);
        ss += __shfl_xor(ss, o);
    }
    __shared__ float red[8];
    int wave = tid >> 6, lane = tid & 63;
    if (lane == 0) { red[wave] = s; red[4 + wave] = ss; }
    __syncthreads();
    s  = red[0] + red[1] + red[2] + red[3];
    ss = red[4] + red[5] + red[6] + red[7];
    float mu   = s * (1.0f / E_);
    float var  = ss * (1.0f / E_) - mu * mu;
    float rstd = rsqrtf(var + 1e-5f);
    float4 gv = ((const float4*)g)[tid];
    float4 bv = ((const float4*)bta)[tid];
    union { bf16_t h[4]; ushort4 u; } pk;
    pk.h[0] = (bf16_t)((v.x - mu) * rstd * gv.x + bv.x);
    pk.h[1] = (bf16_t)((v.y - mu) * rstd * gv.y + bv.y);
    pk.h[2] = (bf16_t)((v.z - mu) * rstd * gv.z + bv.z);
    pk.h[3] = (bf16_t)((v.w - mu) * rstd * gv.w + bv.w);
    ((ushort4*)(out + (size_t)row * E_))[tid] = pk.u;
}

// ------------- split-K reduce (4 bf16 slices) + bias + resid -> fp32 ---
__global__ __launch_bounds__(256) void add_reduce4(
    const bf16_t* __restrict__ p, const float* __restrict__ bias,
    const float* __restrict__ resid, float* __restrict__ out)
{
    int row = blockIdx.x;
    int tid = threadIdx.x;
    size_t off = (size_t)row * E_ + tid * 4;
    float4 v = {0.f, 0.f, 0.f, 0.f};
#pragma unroll
    for (int z = 0; z < 4; ++z) {
        bf16x4 pv = *(const bf16x4*)&p[(size_t)z * NROW * E_ + off];
        v.x += (float)pv[0]; v.y += (float)pv[1];
        v.z += (float)pv[2]; v.w += (float)pv[3];
    }
    float4 bb = ((const float4*)bias)[tid];
    float4 rr = ((const float4*)(resid + (size_t)row * E_))[tid];
    v.x += bb.x + rr.x; v.y += bb.y + rr.y;
    v.z += bb.z + rr.z; v.w += bb.w + rr.w;
    ((float4*)(out + (size_t)row * E_))[tid] = v;
}

// ------------------------- all weight transposes, one dispatch ----------
// W[K][N] fp32 -> Wt[N][K] bf16, 32x32 tiles, segment decoded per block.
__global__ __launch_bounds__(256) void transpose_all(
    const float* __restrict__ Wq, const float* __restrict__ Wk,
    const float* __restrict__ Wv, const float* __restrict__ Wo,
    const float* __restrict__ W1, const float* __restrict__ W2,
    bf16_t* __restrict__ wqkv, bf16_t* __restrict__ wot,
    bf16_t* __restrict__ w1t, bf16_t* __restrict__ w2t)
{
    int l = blockIdx.x;
    const float* W; bf16_t* Wt; int K, N, bx, by;
    if (l < 4096) {
        int seg = l >> 10, r = l & 1023;
        K = E_; N = E_; bx = r & 31; by = r >> 5;
        if      (seg == 0) { W = Wq; Wt = wqkv; }
        else if (seg == 1) { W = Wk; Wt = wqkv + (size_t)E_ * E_; }
        else if (seg == 2) { W = Wv; Wt = wqkv + (size_t)2 * E_ * E_; }
        else               { W = Wo; Wt = wot; }
    } else if (l < 8192) {
        int r = l - 4096; K = E_; N = FF_; bx = r & 127; by = r >> 7;
        W = W1; Wt = w1t;
    } else {
        int r = l - 8192; K = FF_; N = E_; bx = r & 31; by = r >> 5;
        W = W2; Wt = w2t;
    }
    __shared__ float t[32][33];
    int n0 = bx * 32, k0 = by * 32;
    int tx = threadIdx.x & 31, ty = threadIdx.x >> 5;
#pragma unroll
    for (int i = 0; i < 4; ++i)
        t[ty + i * 8][tx] = W[(size_t)(k0 + ty + i * 8) * N + n0 + tx];
    __syncthreads();
#pragma unroll
    for (int i = 0; i < 4; ++i)
        Wt[(size_t)(n0 + ty + i * 8) * K + k0 + tx] = (bf16_t)t[tx][ty + i * 8];
}

// ----------------------------------------------------------- GEMM ------
// m97 structure; split-K via blockIdx.z (bf16 partials [z][M][N]);
// optional V-transpose epilogue for the QKV projection (n0 >= 2*E_).
#define BM 128
#define BN 128
#define BK 32

__global__ __launch_bounds__(256) void gemm_bt(
    const bf16_t* __restrict__ A, const bf16_t* __restrict__ Bt,
    const float* __restrict__ bias, const float* __restrict__ resid,
    void* __restrict__ Cout, bf16_t* __restrict__ vt_out,
    int M, int N, int K, int lda, int ldb,
    int has_bias, int do_relu, int has_resid, int out_bf16)
{
    __shared__ __attribute__((aligned(16))) bf16_t As[BM * BK];
    __shared__ __attribute__((aligned(16))) bf16_t Bs[BN * BK];
    int tid  = threadIdx.x;
    int lane = tid & 63, wave = tid >> 6;
    int m0 = blockIdx.x * BM, n0 = blockIdx.y * BN;
    int wm = (wave & 1) * 64, wn = (wave >> 1) * 64;
    int koff = blockIdx.z * K;
    f32x4 acc[4][4];
#pragma unroll
    for (int i = 0; i < 4; ++i)
#pragma unroll
        for (int j = 0; j < 4; ++j) acc[i][j] = (f32x4){0.f, 0.f, 0.f, 0.f};

    int sr = tid >> 2;
    int sc = (tid & 3) * 8;
    const int kq = (lane >> 4) * 8;
    const int ml = lane & 15;
    const bf16_t* Ag = A  + (size_t)(m0 + sr) * lda + koff + sc;
    const bf16_t* Bg = Bt + (size_t)(n0 + sr) * ldb + koff + sc;
    bf16_t* Al = &As[sr * BK + sc];
    bf16_t* Bl = &Bs[sr * BK + sc];

    for (int k0 = 0; k0 < K; k0 += BK) {
        gll16(Ag + k0, Al);
        gll16(Ag + k0 + (size_t)64 * lda, Al + 64 * BK);
        gll16(Bg + k0, Bl);
        gll16(Bg + k0 + (size_t)64 * ldb, Bl + 64 * BK);
        __syncthreads();
        bf16x8 af[4], bfr[4];
#pragma unroll
        for (int mi = 0; mi < 4; ++mi)
            af[mi] = *(const bf16x8*)&As[(wm + mi * 16 + ml) * BK + kq];
#pragma unroll
        for (int ni = 0; ni < 4; ++ni)
            bfr[ni] = *(const bf16x8*)&Bs[(wn + ni * 16 + ml) * BK + kq];
#pragma unroll
        for (int mi = 0; mi < 4; ++mi)
#pragma unroll
            for (int ni = 0; ni < 4; ++ni)
                acc[mi][ni] = __builtin_amdgcn_mfma_f32_16x16x32_bf16(
                    af[mi], bfr[ni], acc[mi][ni], 0, 0, 0);
        __syncthreads();
    }

    int r4 = (lane >> 4) * 4;
    if (gridDim.z > 1) {
        // split-K partial: bf16 [z][M][N]
        bf16_t* P = (bf16_t*)Cout + (size_t)blockIdx.z * M * N;
#pragma unroll
        for (int mi = 0; mi < 4; ++mi)
#pragma unroll
            for (int ni = 0; ni < 4; ++ni) {
                int col = n0 + wn + ni * 16 + ml;
#pragma unroll
                for (int r = 0; r < 4; ++r) {
                    int row = m0 + wm + mi * 16 + r4 + r;
                    P[(size_t)row * N + col] = (bf16_t)acc[mi][ni][r];
                }
            }
        return;
    }
    if (vt_out && n0 >= 2 * E_) {
        // V slab of QKV: write transposed per-head Vt[bh][d][t]
#pragma unroll
        for (int mi = 0; mi < 4; ++mi)
#pragma unroll
            for (int ni = 0; ni < 4; ++ni) {
                int vcol = n0 + wn + ni * 16 + ml - 2 * E_;
                int h = vcol >> 6, d = vcol & 63;
                int row0 = m0 + wm + mi * 16 + r4;
                int b = row0 >> 11, t = row0 & (T_ - 1);
                union { bf16_t h4[4]; uint2 u; } pk;
#pragma unroll
                for (int r = 0; r < 4; ++r) pk.h4[r] = (bf16_t)acc[mi][ni][r];
                *(uint2*)&vt_out[((size_t)(b * H_ + h) * D_ + d) * T_ + t] = pk.u;
            }
        return;
    }
#pragma unroll
    for (int mi = 0; mi < 4; ++mi) {
#pragma unroll
        for (int ni = 0; ni < 4; ++ni) {
            int col = n0 + wn + ni * 16 + ml;
            float bval = has_bias ? bias[col] : 0.0f;
#pragma unroll
            for (int r = 0; r < 4; ++r) {
                int row = m0 + wm + mi * 16 + r4 + r;
                float v = acc[mi][ni][r] + bval;
                if (do_relu)   v = fmaxf(v, 0.0f);
                if (has_resid) v += resid[(size_t)row * N + col];
                if (out_bf16)
                    ((bf16_t*)Cout)[(size_t)row * N + col] = (bf16_t)v;
                else
                    ((float*)Cout)[(size_t)row * N + col] = v;
            }
        }
    }
}

// ------------------------------------------------- MFMA flash attention -
// Pair (i, NTI-1-i) share the chunk loop; K/V staged once per chunk; reg
// double-buffered staging, one barrier per chunk; per-lane softmax state.
#define PSTR 72

struct TileState {
    f32x4 acc[4];
    float m1, l1;
};

__device__ __forceinline__ void tile_update(
    const bf16x8 kf[2][4], const bf16x8 vf[2][4], const bf16x8 qf[2],
    TileState& st, bf16_t* PsW, int ml, int r4, int kq8,
    bool diag, int ch, int qrow)
{
    f32x4 s[4];
#pragma unroll
    for (int nt = 0; nt < 4; ++nt) {
        s[nt] = (f32x4){0.f, 0.f, 0.f, 0.f};
#pragma unroll
        for (int ks = 0; ks < 2; ++ks)
            s[nt] = __builtin_amdgcn_mfma_f32_16x16x32_bf16(kf[ks][nt], qf[ks], s[nt], 0, 0, 0);
    }
    if (diag) {
#pragma unroll
        for (int nt = 0; nt < 4; ++nt)
#pragma unroll
            for (int r = 0; r < 4; ++r)
                if (ch * 64 + nt * 16 + r4 + r > qrow) s[nt][r] = -INFINITY;
    }
    float mx = -INFINITY;
#pragma unroll
    for (int nt = 0; nt < 4; ++nt)
#pragma unroll
        for (int r = 0; r < 4; ++r) mx = fmaxf(mx, s[nt][r]);
    mx = fmaxf(mx, __shfl_xor(mx, 16));
    mx = fmaxf(mx, __shfl_xor(mx, 32));
    float mn = fmaxf(st.m1, mx);
    float al = __expf(st.m1 - mn);
    st.m1 = mn;
    float sum = 0.f;
#pragma unroll
    for (int nt = 0; nt < 4; ++nt)
#pragma unroll
        for (int r = 0; r < 4; ++r) {
            float p = __expf(s[nt][r] - mn);
            s[nt][r] = p;
            sum += p;
        }
    sum += __shfl_xor(sum, 16);
    sum += __shfl_xor(sum, 32);
    st.l1 = st.l1 * al + sum;
#pragma unroll
    for (int dt = 0; dt < 4; ++dt)
#pragma unroll
        for (int r = 0; r < 4; ++r) st.acc[dt][r] *= al;

#pragma unroll
    for (int nt = 0; nt < 4; ++nt) {
        union { bf16_t h[4]; uint2 u; } pk;
#pragma unroll
        for (int r = 0; r < 4; ++r) pk.h[r] = (bf16_t)s[nt][r];
        *(uint2*)&PsW[ml * PSTR + nt * 16 + r4] = pk.u;
    }
#pragma unroll
    for (int ks = 0; ks < 2; ++ks) {
        bf16x8 pf = *(const bf16x8*)&PsW[ml * PSTR + ks * 32 + kq8];
#pragma unroll
        for (int dt = 0; dt < 4; ++dt)
            st.acc[dt] = __builtin_amdgcn_mfma_f32_16x16x32_bf16(vf[ks][dt], pf, st.acc[dt], 0, 0, 0);
    }
}

__global__ __launch_bounds__(256) void attn_mfma(
    const bf16_t* __restrict__ Qp, const bf16_t* __restrict__ Kp,
    const bf16_t* __restrict__ Vt, bf16_t* __restrict__ O)
{
    __shared__ __attribute__((aligned(16))) bf16_t Ks[2][64 * PSTR];
    __shared__ __attribute__((aligned(16))) bf16_t Vts[2][64 * PSTR];
    __shared__ __attribute__((aligned(16))) bf16_t Ps[4][16 * PSTR];

    int tid = threadIdx.x, lane = tid & 63, wave = tid >> 6;
    int ml  = lane & 15;
    int kq8 = (lane >> 4) * 8;
    int r4  = (lane >> 4) * 4;
    int bh = blockIdx.y, b = bh >> 4, h = bh & 15;
    size_t qk_base = (size_t)b * T_ * QS_ + h * D_;
    size_t vt_base = (size_t)bh * D_ * T_;
    size_t o_base  = (size_t)b * T_ * E_ + h * D_;

    int lo = blockIdx.x, hi = NTI - 1 - blockIdx.x;
    int qlo = lo * 64 + wave * 16;
    int qhi = hi * 64 + wave * 16;

    bf16x8 qfl[2], qfh[2];
#pragma unroll
    for (int ks = 0; ks < 2; ++ks) {
        bf16x8 a = *(const bf16x8*)&Qp[qk_base + (size_t)(qlo + ml) * QS_ + ks * 32 + kq8];
        bf16x8 c = *(const bf16x8*)&Qp[qk_base + (size_t)(qhi + ml) * QS_ + ks * 32 + kq8];
#pragma unroll
        for (int j = 0; j < 8; ++j) {
            a[j] = (bf16_t)((float)a[j] * 0.125f);
            c[j] = (bf16_t)((float)c[j] * 0.125f);
        }
        qfl[ks] = a; qfh[ks] = c;
    }

    TileState stl, sth;
#pragma unroll
    for (int dt = 0; dt < 4; ++dt) {
        stl.acc[dt] = (f32x4){0.f, 0.f, 0.f, 0.f};
        sth.acc[dt] = (f32x4){0.f, 0.f, 0.f, 0.f};
    }
    stl.m1 = -INFINITY; stl.l1 = 0.f;
    sth.m1 = -INFINITY; sth.l1 = 0.f;

    int r0 = tid >> 3, c0 = (tid & 7) * 8;
    int nch = hi + 1;

    {
        const bf16_t* kb = &Kp[qk_base + (size_t)r0 * QS_ + c0];
        const bf16_t* vb = &Vt[vt_base + (size_t)r0 * T_ + c0];
        uint4 k0v = *(const uint4*)kb;
        uint4 k1v = *(const uint4*)(kb + (size_t)32 * QS_);
        uint4 v0v = *(const uint4*)vb;
        uint4 v1v = *(const uint4*)(vb + (size_t)32 * T_);
        *(uint4*)&Ks[0][r0 * PSTR + c0]         = k0v;
        *(uint4*)&Ks[0][(r0 + 32) * PSTR + c0]  = k1v;
        *(uint4*)&Vts[0][r0 * PSTR + c0]        = v0v;
        *(uint4*)&Vts[0][(r0 + 32) * PSTR + c0] = v1v;
    }

    for (int ch = 0; ch < nch; ++ch) {
        int cur = ch & 1, nxt = cur ^ 1;
        __syncthreads();

        uint4 nk0, nk1, nv0, nv1;
        bool pf = (ch + 1 < nch);
        if (pf) {
            const bf16_t* kb = &Kp[qk_base + (size_t)((ch + 1) * 64 + r0) * QS_ + c0];
            const bf16_t* vb = &Vt[vt_base + (size_t)r0 * T_ + (ch + 1) * 64 + c0];
            nk0 = *(const uint4*)kb;
            nk1 = *(const uint4*)(kb + (size_t)32 * QS_);
            nv0 = *(const uint4*)vb;
            nv1 = *(const uint4*)(vb + (size_t)32 * T_);
        }

        bf16x8 kf[2][4], vf[2][4];
#pragma unroll
        for (int ks = 0; ks < 2; ++ks)
#pragma unroll
            for (int nt = 0; nt < 4; ++nt) {
                kf[ks][nt] = *(const bf16x8*)&Ks[cur][(nt * 16 + ml) * PSTR + ks * 32 + kq8];
                vf[ks][nt] = *(const bf16x8*)&Vts[cur][(nt * 16 + ml) * PSTR + ks * 32 + kq8];
            }

        tile_update(kf, vf, qfh, sth, Ps[wave], ml, r4, kq8,
                    ch == hi, ch, qhi + ml);
        if (ch <= lo)
            tile_update(kf, vf, qfl, stl, Ps[wave], ml, r4, kq8,
                        ch == lo, ch, qlo + ml);

        if (pf) {
            *(uint4*)&Ks[nxt][r0 * PSTR + c0]         = nk0;
            *(uint4*)&Ks[nxt][(r0 + 32) * PSTR + c0]  = nk1;
            *(uint4*)&Vts[nxt][r0 * PSTR + c0]        = nv0;
            *(uint4*)&Vts[nxt][(r0 + 32) * PSTR + c0] = nv1;
        }
    }

#pragma unroll
    for (int t = 0; t < 2; ++t) {
        TileState& st = t ? stl : sth;
        int qw = t ? qlo : qhi;
        float inv = 1.0f / st.l1;
#pragma unroll
        for (int dt = 0; dt < 4; ++dt) {
            union { bf16_t h[4]; uint2 u; } pk;
#pragma unroll
            for (int r = 0; r < 4; ++r) pk.h[r] = (bf16_t)(st.acc[dt][r] * inv);
            *(uint2*)&Ps[wave][ml * PSTR + dt * 16 + r4] = pk.u;
        }
        int row = lane >> 2, seg = (lane & 3) * 16;
        bf16x8 o0 = *(const bf16x8*)&Ps[wave][row * PSTR + seg];
        bf16x8 o1 = *(const bf16x8*)&Ps[wave][row * PSTR + seg + 8];
        size_t gp = o_base + (size_t)(qw + row) * E_ + seg;
        *(bf16x8*)&O[gp]     = o0;
        *(bf16x8*)&O[gp + 8] = o1;
    }
}

// ------------------------------------------------------------ launch ---
extern "C" void kernel_launch(void* const* d_in, const int* in_sizes, int n_in,
                              void* d_out, int out_size, void* d_ws, size_t ws_size,
                              hipStream_t stream)
{
    const float* x    = (const float*)d_in[0];
    const float* ln1g = (const float*)d_in[1];
    const float* ln1b = (const float*)d_in[2];
    const float* Wq   = (const float*)d_in[3];
    const float* Wk   = (const float*)d_in[4];
    const float* Wv   = (const float*)d_in[5];
    const float* Wo   = (const float*)d_in[6];
    const float* bo   = (const float*)d_in[7];
    const float* ln2g = (const float*)d_in[8];
    const float* ln2b = (const float*)d_in[9];
    const float* W1   = (const float*)d_in[10];
    const float* b1   = (const float*)d_in[11];
    const float* W2   = (const float*)d_in[12];
    const float* b2   = (const float*)d_in[13];

    char* ws = (char*)d_ws;
    const size_t MB = 1024ull * 1024ull;
    bf16_t* wqkv = (bf16_t*)(ws + 0 * MB);    // 3072x1024 bf16
    bf16_t* wot  = (bf16_t*)(ws + 6 * MB);    // 1024x1024 bf16
    bf16_t* w1t  = (bf16_t*)(ws + 8 * MB);    // 4096x1024 bf16
    bf16_t* w2t  = (bf16_t*)(ws + 16 * MB);   // 1024x4096 bf16
    bf16_t* xn   = (bf16_t*)(ws + 24 * MB);   // dead after QKV gemm
    bf16_t* QKV  = (bf16_t*)(ws + 32 * MB);   // Q,K slabs; dead after attn
    bf16_t* att  = (bf16_t*)(ws + 56 * MB);   // dead after Wo gemm
    float*  x1   = (float*)(ws + 64 * MB);    // live through add_reduce4
    bf16_t* hb   = (bf16_t*)(ws + 80 * MB);
    bf16_t* h1   = (bf16_t*)(ws + 88 * MB);   // 32 MB
    bf16_t* Vtb  = (bf16_t*)(ws + 88 * MB);   // 8 MB alias; dead before h1 write
    bf16_t* part = (bf16_t*)(ws + 24 * MB);   // 4x8 MB bf16 split-K partials
                                              // (xn+QKV dead at Wo; +att dead at down)

    dim3 blk(256);

    transpose_all<<<dim3(12288), blk, 0, stream>>>(
        Wq, Wk, Wv, Wo, W1, W2, wqkv, wot, w1t, w2t);

    ln_kernel<<<dim3(NROW), blk, 0, stream>>>(x, ln1g, ln1b, xn);

    // fused QKV projection; V slab written transposed per-head into Vtb
    gemm_bt<<<dim3(NROW / BM, QS_ / BN), blk, 0, stream>>>(
        xn, wqkv, nullptr, nullptr, QKV, Vtb, NROW, QS_, E_, E_, E_, 0, 0, 0, 1);

    attn_mfma<<<dim3(NTI / 2, B_ * H_), blk, 0, stream>>>(
        QKV, QKV + E_, Vtb, att);

    // Wo projection: split-K x4, bf16 partials -> reduce + LN2 fused
    gemm_bt<<<dim3(NROW / BM, E_ / BN, 4), blk, 0, stream>>>(
        att, wot, nullptr, nullptr, part, nullptr, NROW, E_, E_ / 4, E_, E_, 0, 0, 0, 0);
    ln_reduce4<<<dim3(NROW), blk, 0, stream>>>(
        part, bo, x, x1, ln2g, ln2b, hb);

    // MLP up + bias + relu
    gemm_bt<<<dim3(NROW / BM, FF_ / BN), blk, 0, stream>>>(
        hb, w1t, b1, nullptr, h1, nullptr, NROW, FF_, E_, E_, E_, 1, 1, 0, 1);

    // MLP down: split-K x4, bf16 partials -> reduce + b2 + resid
    gemm_bt<<<dim3(NROW / BM, E_ / BN, 4), blk, 0, stream>>>(
        h1, w2t, nullptr, nullptr, part, nullptr, NROW, E_, FF_ / 4, FF_, FF_, 0, 0, 0, 0);
    add_reduce4<<<dim3(NROW), blk, 0, stream>>>(
        part, b2, x1, (float*)d_out);
}

// Round 7
// 342.560 us; speedup vs baseline: 3.8233x; 1.0914x over previous
//
#include <hip/hip_runtime.h>
#include <cmath>
#include <cstdint>
#include <cstddef>

typedef __bf16 bf16_t;
typedef __bf16 bf16x8 __attribute__((ext_vector_type(8)));
typedef float  f32x4  __attribute__((ext_vector_type(4)));

#define B_   2
#define T_   2048
#define E_   1024
#define H_   16
#define D_   64
#define FF_  4096
#define NROW (B_ * T_)   // 4096
#define QS_  (3 * E_)    // packed QKV row stride
#define NTI  (T_ / 64)   // 32 q-tiles

// ---------------------------------------------------------------- LN ----
__global__ __launch_bounds__(256) void ln_kernel(
    const float* __restrict__ x, const float* __restrict__ g,
    const float* __restrict__ bta, bf16_t* __restrict__ out)
{
    int row = blockIdx.x;
    int tid = threadIdx.x;
    const float4* xr = (const float4*)(x + (size_t)row * E_);
    float4 v = xr[tid];
    float s  = v.x + v.y + v.z + v.w;
    float ss = v.x * v.x + v.y * v.y + v.z * v.z + v.w * v.w;
#pragma unroll
    for (int off = 32; off; off >>= 1) {
        s  += __shfl_xor(s, off);
        ss += __shfl_xor(ss, off);
    }
    __shared__ float red[8];
    int wave = tid >> 6, lane = tid & 63;
    if (lane == 0) { red[wave] = s; red[4 + wave] = ss; }
    __syncthreads();
    s  = red[0] + red[1] + red[2] + red[3];
    ss = red[4] + red[5] + red[6] + red[7];
    float mu   = s * (1.0f / E_);
    float var  = ss * (1.0f / E_) - mu * mu;
    float rstd = rsqrtf(var + 1e-5f);
    float4 gv = ((const float4*)g)[tid];
    float4 bv = ((const float4*)bta)[tid];
    union { bf16_t h[4]; ushort4 u; } pk;
    pk.h[0] = (bf16_t)((v.x - mu) * rstd * gv.x + bv.x);
    pk.h[1] = (bf16_t)((v.y - mu) * rstd * gv.y + bv.y);
    pk.h[2] = (bf16_t)((v.z - mu) * rstd * gv.z + bv.z);
    pk.h[3] = (bf16_t)((v.w - mu) * rstd * gv.w + bv.w);
    ((ushort4*)(out + (size_t)row * E_))[tid] = pk.u;
}

// ---------------- split-K reduce (2 fp32 slices) + bias + resid + LN ---
__global__ __launch_bounds__(256) void ln_reduce2(
    const float* __restrict__ p, const float* __restrict__ bias,
    const float* __restrict__ resid, float* __restrict__ x1,
    const float* __restrict__ g, const float* __restrict__ bta,
    bf16_t* __restrict__ out)
{
    int row = blockIdx.x;
    int tid = threadIdx.x;
    size_t off = (size_t)row * E_;
    float4 v0 = ((const float4*)(p + off))[tid];
    float4 v1 = ((const float4*)(p + (size_t)NROW * E_ + off))[tid];
    float4 bb = ((const float4*)bias)[tid];
    float4 rr = ((const float4*)(resid + off))[tid];
    float4 v;
    v.x = v0.x + v1.x + bb.x + rr.x;
    v.y = v0.y + v1.y + bb.y + rr.y;
    v.z = v0.z + v1.z + bb.z + rr.z;
    v.w = v0.w + v1.w + bb.w + rr.w;
    ((float4*)(x1 + off))[tid] = v;
    float s  = v.x + v.y + v.z + v.w;
    float ss = v.x * v.x + v.y * v.y + v.z * v.z + v.w * v.w;
#pragma unroll
    for (int o = 32; o; o >>= 1) {
        s  += __shfl_xor(s, o);
        ss += __shfl_xor(ss, o);
    }
    __shared__ float red[8];
    int wave = tid >> 6, lane = tid & 63;
    if (lane == 0) { red[wave] = s; red[4 + wave] = ss; }
    __syncthreads();
    s  = red[0] + red[1] + red[2] + red[3];
    ss = red[4] + red[5] + red[6] + red[7];
    float mu   = s * (1.0f / E_);
    float var  = ss * (1.0f / E_) - mu * mu;
    float rstd = rsqrtf(var + 1e-5f);
    float4 gv = ((const float4*)g)[tid];
    float4 bv = ((const float4*)bta)[tid];
    union { bf16_t h[4]; ushort4 u; } pk;
    pk.h[0] = (bf16_t)((v.x - mu) * rstd * gv.x + bv.x);
    pk.h[1] = (bf16_t)((v.y - mu) * rstd * gv.y + bv.y);
    pk.h[2] = (bf16_t)((v.z - mu) * rstd * gv.z + bv.z);
    pk.h[3] = (bf16_t)((v.w - mu) * rstd * gv.w + bv.w);
    ((ushort4*)(out + off))[tid] = pk.u;
}

// ---------------- split-K reduce (2 fp32 slices) + bias + resid --------
__global__ __launch_bounds__(256) void add_reduce2(
    const float* __restrict__ p, const float* __restrict__ bias,
    const float* __restrict__ resid, float* __restrict__ out)
{
    int row = blockIdx.x;
    int tid = threadIdx.x;
    size_t off = (size_t)row * E_;
    float4 v0 = ((const float4*)(p + off))[tid];
    float4 v1 = ((const float4*)(p + (size_t)NROW * E_ + off))[tid];
    float4 bb = ((const float4*)bias)[tid];
    float4 rr = ((const float4*)(resid + off))[tid];
    float4 v;
    v.x = v0.x + v1.x + bb.x + rr.x;
    v.y = v0.y + v1.y + bb.y + rr.y;
    v.z = v0.z + v1.z + bb.z + rr.z;
    v.w = v0.w + v1.w + bb.w + rr.w;
    ((float4*)(out + off))[tid] = v;
}

// ------------------------- all weight transposes, one dispatch ----------
__global__ __launch_bounds__(256) void transpose_all(
    const float* __restrict__ Wq, const float* __restrict__ Wk,
    const float* __restrict__ Wv, const float* __restrict__ Wo,
    const float* __restrict__ W1, const float* __restrict__ W2,
    bf16_t* __restrict__ wqkv, bf16_t* __restrict__ wot,
    bf16_t* __restrict__ w1t, bf16_t* __restrict__ w2t)
{
    int l = blockIdx.x;
    const float* W; bf16_t* Wt; int K, N, bx, by;
    if (l < 4096) {
        int seg = l >> 10, r = l & 1023;
        K = E_; N = E_; bx = r & 31; by = r >> 5;
        if      (seg == 0) { W = Wq; Wt = wqkv; }
        else if (seg == 1) { W = Wk; Wt = wqkv + (size_t)E_ * E_; }
        else if (seg == 2) { W = Wv; Wt = wqkv + (size_t)2 * E_ * E_; }
        else               { W = Wo; Wt = wot; }
    } else if (l < 8192) {
        int r = l - 4096; K = E_; N = FF_; bx = r & 127; by = r >> 7;
        W = W1; Wt = w1t;
    } else {
        int r = l - 8192; K = FF_; N = E_; bx = r & 31; by = r >> 5;
        W = W2; Wt = w2t;
    }
    __shared__ float t[32][33];
    int n0 = bx * 32, k0 = by * 32;
    int tx = threadIdx.x & 31, ty = threadIdx.x >> 5;
#pragma unroll
    for (int i = 0; i < 4; ++i)
        t[ty + i * 8][tx] = W[(size_t)(k0 + ty + i * 8) * N + n0 + tx];
    __syncthreads();
#pragma unroll
    for (int i = 0; i < 4; ++i)
        Wt[(size_t)(n0 + ty + i * 8) * K + k0 + tx] = (bf16_t)t[tx][ty + i * 8];
}

// ----------------------------------------------------------- GEMM ------
// Single-barrier register-double-buffered K-loop (attention-kernel pattern):
// prefetch next tile into VGPRs right after the barrier, MFMA on buf[cur],
// ds_write prefetch to buf[nxt]. Split-K via blockIdx.z (fp32 partials).
// Optional V-transpose epilogue for the QKV projection (n0 >= 2*E_).
#define BM 128
#define BN 128
#define BK 32

__global__ __launch_bounds__(256) void gemm_bt(
    const bf16_t* __restrict__ A, const bf16_t* __restrict__ Bt,
    const float* __restrict__ bias, const float* __restrict__ resid,
    void* __restrict__ Cout, bf16_t* __restrict__ vt_out,
    int M, int N, int K, int lda, int ldb,
    int has_bias, int do_relu, int has_resid, int out_bf16)
{
    __shared__ __attribute__((aligned(16))) bf16_t As[2][BM * BK];
    __shared__ __attribute__((aligned(16))) bf16_t Bs[2][BN * BK];
    int tid  = threadIdx.x;
    int lane = tid & 63, wave = tid >> 6;
    int m0 = blockIdx.x * BM, n0 = blockIdx.y * BN;
    int wm = (wave & 1) * 64, wn = (wave >> 1) * 64;
    int koff = blockIdx.z * K;
    f32x4 acc[4][4];
#pragma unroll
    for (int i = 0; i < 4; ++i)
#pragma unroll
        for (int j = 0; j < 4; ++j) acc[i][j] = (f32x4){0.f, 0.f, 0.f, 0.f};

    int sr = tid >> 2;            // 0..63 (rows sr, sr+64)
    int sc = (tid & 3) * 8;       // 0,8,16,24
    const int kq = (lane >> 4) * 8;
    const int ml = lane & 15;
    const bf16_t* Ag = A  + (size_t)(m0 + sr) * lda + koff + sc;
    const bf16_t* Bg = Bt + (size_t)(n0 + sr) * ldb + koff + sc;
    int niter = K / BK;

    // prologue: stage k-iter 0 into buffer 0
    {
        uint4 ra0 = *(const uint4*)Ag;
        uint4 ra1 = *(const uint4*)(Ag + (size_t)64 * lda);
        uint4 rb0 = *(const uint4*)Bg;
        uint4 rb1 = *(const uint4*)(Bg + (size_t)64 * ldb);
        *(uint4*)&As[0][sr * BK + sc]        = ra0;
        *(uint4*)&As[0][(sr + 64) * BK + sc] = ra1;
        *(uint4*)&Bs[0][sr * BK + sc]        = rb0;
        *(uint4*)&Bs[0][(sr + 64) * BK + sc] = rb1;
    }

    for (int it = 0; it < niter; ++it) {
        int cur = it & 1, nxt = cur ^ 1;
        __syncthreads();   // buf[cur] ready; prev iter's reads of buf[nxt] done

        // issue next tile's global loads (no wait — land during MFMA)
        uint4 ra0, ra1, rb0, rb1;
        bool pf = (it + 1 < niter);
        if (pf) {
            int k0 = (it + 1) * BK;
            ra0 = *(const uint4*)(Ag + k0);
            ra1 = *(const uint4*)(Ag + k0 + (size_t)64 * lda);
            rb0 = *(const uint4*)(Bg + k0);
            rb1 = *(const uint4*)(Bg + k0 + (size_t)64 * ldb);
        }

        bf16x8 af[4], bfr[4];
#pragma unroll
        for (int mi = 0; mi < 4; ++mi)
            af[mi] = *(const bf16x8*)&As[cur][(wm + mi * 16 + ml) * BK + kq];
#pragma unroll
        for (int ni = 0; ni < 4; ++ni)
            bfr[ni] = *(const bf16x8*)&Bs[cur][(wn + ni * 16 + ml) * BK + kq];
#pragma unroll
        for (int mi = 0; mi < 4; ++mi)
#pragma unroll
            for (int ni = 0; ni < 4; ++ni)
                acc[mi][ni] = __builtin_amdgcn_mfma_f32_16x16x32_bf16(
                    af[mi], bfr[ni], acc[mi][ni], 0, 0, 0);

        if (pf) {
            *(uint4*)&As[nxt][sr * BK + sc]        = ra0;
            *(uint4*)&As[nxt][(sr + 64) * BK + sc] = ra1;
            *(uint4*)&Bs[nxt][sr * BK + sc]        = rb0;
            *(uint4*)&Bs[nxt][(sr + 64) * BK + sc] = rb1;
        }
    }

    int r4 = (lane >> 4) * 4;
    if (gridDim.z > 1) {
        // split-K partial: fp32 [z][M][N]
        float* P = (float*)Cout + (size_t)blockIdx.z * M * N;
#pragma unroll
        for (int mi = 0; mi < 4; ++mi)
#pragma unroll
            for (int ni = 0; ni < 4; ++ni) {
                int col = n0 + wn + ni * 16 + ml;
#pragma unroll
                for (int r = 0; r < 4; ++r) {
                    int row = m0 + wm + mi * 16 + r4 + r;
                    P[(size_t)row * N + col] = acc[mi][ni][r];
                }
            }
        return;
    }
    if (vt_out && n0 >= 2 * E_) {
        // V slab of QKV: write transposed per-head Vt[bh][d][t]
#pragma unroll
        for (int mi = 0; mi < 4; ++mi)
#pragma unroll
            for (int ni = 0; ni < 4; ++ni) {
                int vcol = n0 + wn + ni * 16 + ml - 2 * E_;
                int h = vcol >> 6, d = vcol & 63;
                int row0 = m0 + wm + mi * 16 + r4;
                int b = row0 >> 11, t = row0 & (T_ - 1);
                union { bf16_t h4[4]; uint2 u; } pk;
#pragma unroll
                for (int r = 0; r < 4; ++r) pk.h4[r] = (bf16_t)acc[mi][ni][r];
                *(uint2*)&vt_out[((size_t)(b * H_ + h) * D_ + d) * T_ + t] = pk.u;
            }
        return;
    }
#pragma unroll
    for (int mi = 0; mi < 4; ++mi) {
#pragma unroll
        for (int ni = 0; ni < 4; ++ni) {
            int col = n0 + wn + ni * 16 + ml;
            float bval = has_bias ? bias[col] : 0.0f;
#pragma unroll
            for (int r = 0; r < 4; ++r) {
                int row = m0 + wm + mi * 16 + r4 + r;
                float v = acc[mi][ni][r] + bval;
                if (do_relu)   v = fmaxf(v, 0.0f);
                if (has_resid) v += resid[(size_t)row * N + col];
                if (out_bf16)
                    ((bf16_t*)Cout)[(size_t)row * N + col] = (bf16_t)v;
                else
                    ((float*)Cout)[(size_t)row * N + col] = v;
            }
        }
    }
}

// ------------------------------------------------- MFMA flash attention -
#define PSTR 72

struct TileState {
    f32x4 acc[4];
    float m1, l1;
};

__device__ __forceinline__ void tile_update(
    const bf16x8 kf[2][4], const bf16x8 vf[2][4], const bf16x8 qf[2],
    TileState& st, bf16_t* PsW, int ml, int r4, int kq8,
    bool diag, int ch, int qrow)
{
    f32x4 s[4];
#pragma unroll
    for (int nt = 0; nt < 4; ++nt) {
        s[nt] = (f32x4){0.f, 0.f, 0.f, 0.f};
#pragma unroll
        for (int ks = 0; ks < 2; ++ks)
            s[nt] = __builtin_amdgcn_mfma_f32_16x16x32_bf16(kf[ks][nt], qf[ks], s[nt], 0, 0, 0);
    }
    if (diag) {
#pragma unroll
        for (int nt = 0; nt < 4; ++nt)
#pragma unroll
            for (int r = 0; r < 4; ++r)
                if (ch * 64 + nt * 16 + r4 + r > qrow) s[nt][r] = -INFINITY;
    }
    float mx = -INFINITY;
#pragma unroll
    for (int nt = 0; nt < 4; ++nt)
#pragma unroll
        for (int r = 0; r < 4; ++r) mx = fmaxf(mx, s[nt][r]);
    mx = fmaxf(mx, __shfl_xor(mx, 16));
    mx = fmaxf(mx, __shfl_xor(mx, 32));
    float mn = fmaxf(st.m1, mx);
    float al = __expf(st.m1 - mn);
    st.m1 = mn;
    float sum = 0.f;
#pragma unroll
    for (int nt = 0; nt < 4; ++nt)
#pragma unroll
        for (int r = 0; r < 4; ++r) {
            float p = __expf(s[nt][r] - mn);
            s[nt][r] = p;
            sum += p;
        }
    sum += __shfl_xor(sum, 16);
    sum += __shfl_xor(sum, 32);
    st.l1 = st.l1 * al + sum;
#pragma unroll
    for (int dt = 0; dt < 4; ++dt)
#pragma unroll
        for (int r = 0; r < 4; ++r) st.acc[dt][r] *= al;

#pragma unroll
    for (int nt = 0; nt < 4; ++nt) {
        union { bf16_t h[4]; uint2 u; } pk;
#pragma unroll
        for (int r = 0; r < 4; ++r) pk.h[r] = (bf16_t)s[nt][r];
        *(uint2*)&PsW[ml * PSTR + nt * 16 + r4] = pk.u;
    }
#pragma unroll
    for (int ks = 0; ks < 2; ++ks) {
        bf16x8 pf = *(const bf16x8*)&PsW[ml * PSTR + ks * 32 + kq8];
#pragma unroll
        for (int dt = 0; dt < 4; ++dt)
            st.acc[dt] = __builtin_amdgcn_mfma_f32_16x16x32_bf16(vf[ks][dt], pf, st.acc[dt], 0, 0, 0);
    }
}

__global__ __launch_bounds__(256) void attn_mfma(
    const bf16_t* __restrict__ Qp, const bf16_t* __restrict__ Kp,
    const bf16_t* __restrict__ Vt, bf16_t* __restrict__ O)
{
    __shared__ __attribute__((aligned(16))) bf16_t Ks[2][64 * PSTR];
    __shared__ __attribute__((aligned(16))) bf16_t Vts[2][64 * PSTR];
    __shared__ __attribute__((aligned(16))) bf16_t Ps[4][16 * PSTR];

    int tid = threadIdx.x, lane = tid & 63, wave = tid >> 6;
    int ml  = lane & 15;
    int kq8 = (lane >> 4) * 8;
    int r4  = (lane >> 4) * 4;
    int bh = blockIdx.y, b = bh >> 4, h = bh & 15;
    size_t qk_base = (size_t)b * T_ * QS_ + h * D_;
    size_t vt_base = (size_t)bh * D_ * T_;
    size_t o_base  = (size_t)b * T_ * E_ + h * D_;

    int lo = blockIdx.x, hi = NTI - 1 - blockIdx.x;
    int qlo = lo * 64 + wave * 16;
    int qhi = hi * 64 + wave * 16;

    bf16x8 qfl[2], qfh[2];
#pragma unroll
    for (int ks = 0; ks < 2; ++ks) {
        bf16x8 a = *(const bf16x8*)&Qp[qk_base + (size_t)(qlo + ml) * QS_ + ks * 32 + kq8];
        bf16x8 c = *(const bf16x8*)&Qp[qk_base + (size_t)(qhi + ml) * QS_ + ks * 32 + kq8];
#pragma unroll
        for (int j = 0; j < 8; ++j) {
            a[j] = (bf16_t)((float)a[j] * 0.125f);
            c[j] = (bf16_t)((float)c[j] * 0.125f);
        }
        qfl[ks] = a; qfh[ks] = c;
    }

    TileState stl, sth;
#pragma unroll
    for (int dt = 0; dt < 4; ++dt) {
        stl.acc[dt] = (f32x4){0.f, 0.f, 0.f, 0.f};
        sth.acc[dt] = (f32x4){0.f, 0.f, 0.f, 0.f};
    }
    stl.m1 = -INFINITY; stl.l1 = 0.f;
    sth.m1 = -INFINITY; sth.l1 = 0.f;

    int r0 = tid >> 3, c0 = (tid & 7) * 8;
    int nch = hi + 1;

    {
        const bf16_t* kb = &Kp[qk_base + (size_t)r0 * QS_ + c0];
        const bf16_t* vb = &Vt[vt_base + (size_t)r0 * T_ + c0];
        uint4 k0v = *(const uint4*)kb;
        uint4 k1v = *(const uint4*)(kb + (size_t)32 * QS_);
        uint4 v0v = *(const uint4*)vb;
        uint4 v1v = *(const uint4*)(vb + (size_t)32 * T_);
        *(uint4*)&Ks[0][r0 * PSTR + c0]         = k0v;
        *(uint4*)&Ks[0][(r0 + 32) * PSTR + c0]  = k1v;
        *(uint4*)&Vts[0][r0 * PSTR + c0]        = v0v;
        *(uint4*)&Vts[0][(r0 + 32) * PSTR + c0] = v1v;
    }

    for (int ch = 0; ch < nch; ++ch) {
        int cur = ch & 1, nxt = cur ^ 1;
        __syncthreads();

        uint4 nk0, nk1, nv0, nv1;
        bool pf = (ch + 1 < nch);
        if (pf) {
            const bf16_t* kb = &Kp[qk_base + (size_t)((ch + 1) * 64 + r0) * QS_ + c0];
            const bf16_t* vb = &Vt[vt_base + (size_t)r0 * T_ + (ch + 1) * 64 + c0];
            nk0 = *(const uint4*)kb;
            nk1 = *(const uint4*)(kb + (size_t)32 * QS_);
            nv0 = *(const uint4*)vb;
            nv1 = *(const uint4*)(vb + (size_t)32 * T_);
        }

        bf16x8 kf[2][4], vf[2][4];
#pragma unroll
        for (int ks = 0; ks < 2; ++ks)
#pragma unroll
            for (int nt = 0; nt < 4; ++nt) {
                kf[ks][nt] = *(const bf16x8*)&Ks[cur][(nt * 16 + ml) * PSTR + ks * 32 + kq8];
                vf[ks][nt] = *(const bf16x8*)&Vts[cur][(nt * 16 + ml) * PSTR + ks * 32 + kq8];
            }

        tile_update(kf, vf, qfh, sth, Ps[wave], ml, r4, kq8,
                    ch == hi, ch, qhi + ml);
        if (ch <= lo)
            tile_update(kf, vf, qfl, stl, Ps[wave], ml, r4, kq8,
                        ch == lo, ch, qlo + ml);

        if (pf) {
            *(uint4*)&Ks[nxt][r0 * PSTR + c0]         = nk0;
            *(uint4*)&Ks[nxt][(r0 + 32) * PSTR + c0]  = nk1;
            *(uint4*)&Vts[nxt][r0 * PSTR + c0]        = nv0;
            *(uint4*)&Vts[nxt][(r0 + 32) * PSTR + c0] = nv1;
        }
    }

#pragma unroll
    for (int t = 0; t < 2; ++t) {
        TileState& st = t ? stl : sth;
        int qw = t ? qlo : qhi;
        float inv = 1.0f / st.l1;
#pragma unroll
        for (int dt = 0; dt < 4; ++dt) {
            union { bf16_t h[4]; uint2 u; } pk;
#pragma unroll
            for (int r = 0; r < 4; ++r) pk.h[r] = (bf16_t)(st.acc[dt][r] * inv);
            *(uint2*)&Ps[wave][ml * PSTR + dt * 16 + r4] = pk.u;
        }
        int row = lane >> 2, seg = (lane & 3) * 16;
        bf16x8 o0 = *(const bf16x8*)&Ps[wave][row * PSTR + seg];
        bf16x8 o1 = *(const bf16x8*)&Ps[wave][row * PSTR + seg + 8];
        size_t gp = o_base + (size_t)(qw + row) * E_ + seg;
        *(bf16x8*)&O[gp]     = o0;
        *(bf16x8*)&O[gp + 8] = o1;
    }
}

// ------------------------------------------------------------ launch ---
extern "C" void kernel_launch(void* const* d_in, const int* in_sizes, int n_in,
                              void* d_out, int out_size, void* d_ws, size_t ws_size,
                              hipStream_t stream)
{
    const float* x    = (const float*)d_in[0];
    const float* ln1g = (const float*)d_in[1];
    const float* ln1b = (const float*)d_in[2];
    const float* Wq   = (const float*)d_in[3];
    const float* Wk   = (const float*)d_in[4];
    const float* Wv   = (const float*)d_in[5];
    const float* Wo   = (const float*)d_in[6];
    const float* bo   = (const float*)d_in[7];
    const float* ln2g = (const float*)d_in[8];
    const float* ln2b = (const float*)d_in[9];
    const float* W1   = (const float*)d_in[10];
    const float* b1   = (const float*)d_in[11];
    const float* W2   = (const float*)d_in[12];
    const float* b2   = (const float*)d_in[13];

    char* ws = (char*)d_ws;
    const size_t MB = 1024ull * 1024ull;
    bf16_t* wqkv = (bf16_t*)(ws + 0 * MB);    // 3072x1024 bf16
    bf16_t* wot  = (bf16_t*)(ws + 6 * MB);    // 1024x1024 bf16
    bf16_t* w1t  = (bf16_t*)(ws + 8 * MB);    // 4096x1024 bf16
    bf16_t* w2t  = (bf16_t*)(ws + 16 * MB);   // 1024x4096 bf16
    bf16_t* xn   = (bf16_t*)(ws + 24 * MB);   // dead after QKV gemm
    bf16_t* QKV  = (bf16_t*)(ws + 32 * MB);   // Q,K slabs; dead after attn
    bf16_t* att  = (bf16_t*)(ws + 56 * MB);   // dead after Wo gemm
    float*  x1   = (float*)(ws + 64 * MB);    // live through add_reduce2
    bf16_t* hb   = (bf16_t*)(ws + 80 * MB);
    bf16_t* h1   = (bf16_t*)(ws + 88 * MB);   // 32 MB
    bf16_t* Vtb  = (bf16_t*)(ws + 88 * MB);   // 8 MB alias; dead before h1 write
    float*  part = (float*)(ws + 24 * MB);    // 2x16 MB fp32 split-K partials
                                              // (xn+QKV dead at Wo; +att dead at down)

    dim3 blk(256);

    transpose_all<<<dim3(12288), blk, 0, stream>>>(
        Wq, Wk, Wv, Wo, W1, W2, wqkv, wot, w1t, w2t);

    ln_kernel<<<dim3(NROW), blk, 0, stream>>>(x, ln1g, ln1b, xn);

    // fused QKV projection; V slab written transposed per-head into Vtb
    gemm_bt<<<dim3(NROW / BM, QS_ / BN), blk, 0, stream>>>(
        xn, wqkv, nullptr, nullptr, QKV, Vtb, NROW, QS_, E_, E_, E_, 0, 0, 0, 1);

    attn_mfma<<<dim3(NTI / 2, B_ * H_), blk, 0, stream>>>(
        QKV, QKV + E_, Vtb, att);

    // Wo projection: split-K x2 fp32 partials -> reduce + LN2 fused
    gemm_bt<<<dim3(NROW / BM, E_ / BN, 2), blk, 0, stream>>>(
        att, wot, nullptr, nullptr, part, nullptr, NROW, E_, E_ / 2, E_, E_, 0, 0, 0, 0);
    ln_reduce2<<<dim3(NROW), blk, 0, stream>>>(
        part, bo, x, x1, ln2g, ln2b, hb);

    // MLP up + bias + relu
    gemm_bt<<<dim3(NROW / BM, FF_ / BN), blk, 0, stream>>>(
        hb, w1t, b1, nullptr, h1, nullptr, NROW, FF_, E_, E_, E_, 1, 1, 0, 1);

    // MLP down: split-K x2 fp32 partials -> reduce + b2 + resid
    gemm_bt<<<dim3(NROW / BM, E_ / BN, 2), blk, 0, stream>>>(
        h1, w2t, nullptr, nullptr, part, nullptr, NROW, E_, FF_ / 2, FF_, FF_, 0, 0, 0, 0);
    add_reduce2<<<dim3(NROW), blk, 0, stream>>>(
        part, b2, x1, (float*)d_out);
}